// Round 10
// baseline (4429.977 us; speedup 1.0000x reference)
//
#include <hip/hip_runtime.h>
#include <math.h>

#define N_NODES 25600
#define F_IN    128
#define H_GNN   256
#define D_MLP   512
#define E_EDGE  409600
#define B_GR    256
#define NPG_    100
#define R_LSTM  512
#define V_OUT   32000

typedef __bf16 bf16x8 __attribute__((ext_vector_type(8)));
typedef float  f32x4  __attribute__((ext_vector_type(4)));
typedef unsigned short u16x8 __attribute__((ext_vector_type(8)));

__device__ __forceinline__ unsigned short f2bf(float x) {
    unsigned u = __builtin_bit_cast(unsigned, x);
    unsigned r = (u + 0x7FFFu + ((u >> 16) & 1u)) >> 16;
    return (unsigned short)r;
}

// ---------------------------------------------------------------------------
// Generic f32 tiled GEMM — small GEMMs (weight folds, W2, inp0).
// ---------------------------------------------------------------------------
template<bool TRANSB>
__global__ __launch_bounds__(256)
void gemm_tile(const float* __restrict__ A, const float* __restrict__ B,
               float* __restrict__ C, const float* __restrict__ bias,
               int M, int N, int K, int lda, int ldb, int ldc, int kChunk)
{
    __shared__ float As[16][68];
    __shared__ float Bs[16][68];
    const int tid = threadIdx.x;
    const int n0 = blockIdx.x * 64;
    const int m0 = blockIdx.y * 64;
    const int z  = blockIdx.z;
    const int k0 = z * kChunk;
    const int k1 = min(K, k0 + kChunk);
    const int ty = tid >> 4, tx = tid & 15;
    float acc[4][4] = {};

    for (int kb = k0; kb < k1; kb += 16) {
        {
            const int r = tid >> 4, c = tid & 15;
            #pragma unroll
            for (int i = 0; i < 4; ++i) {
                int rr = r + i * 16;
                int gm = m0 + rr, gk = kb + c;
                As[c][rr] = (gm < M && gk < k1) ? A[gm * lda + gk] : 0.f;
            }
        }
        if (!TRANSB) {
            const int r = tid >> 6, c = tid & 63;
            #pragma unroll
            for (int i = 0; i < 4; ++i) {
                int rr = r + i * 4;
                int gk = kb + rr, gn = n0 + c;
                Bs[rr][c] = (gk < k1 && gn < N) ? B[gk * ldb + gn] : 0.f;
            }
        } else {
            const int r = tid & 15, c = tid >> 4;
            #pragma unroll
            for (int i = 0; i < 4; ++i) {
                int cc = c + i * 16;
                int gk = kb + r, gn = n0 + cc;
                Bs[r][cc] = (gk < k1 && gn < N) ? B[gn * ldb + gk] : 0.f;
            }
        }
        __syncthreads();
        #pragma unroll
        for (int kk = 0; kk < 16; ++kk) {
            float a[4], b[4];
            #pragma unroll
            for (int i = 0; i < 4; ++i) a[i] = As[kk][ty * 4 + i];
            #pragma unroll
            for (int j = 0; j < 4; ++j) b[j] = Bs[kk][tx * 4 + j];
            #pragma unroll
            for (int i = 0; i < 4; ++i)
                #pragma unroll
                for (int j = 0; j < 4; ++j)
                    acc[i][j] = fmaf(a[i], b[j], acc[i][j]);
        }
        __syncthreads();
    }

    const bool split = (gridDim.z > 1);
    #pragma unroll
    for (int i = 0; i < 4; ++i) {
        int gm = m0 + ty * 4 + i;
        if (gm >= M) continue;
        #pragma unroll
        for (int j = 0; j < 4; ++j) {
            int gn = n0 + tx * 4 + j;
            if (gn >= N) continue;
            float v = acc[i][j];
            if (bias != nullptr && z == 0) v += bias[gn];
            if (split) atomicAdd(&C[gm * ldc + gn], v);
            else       C[gm * ldc + gn] = v;
        }
    }
}

// ---------------------------------------------------------------------------
// Big-tile f32 GEMM: 128x128 tile, 8x8 micro-tile, exact f32.
// ---------------------------------------------------------------------------
__global__ __launch_bounds__(256)
void gemm_f32_big(const float* __restrict__ A, const float* __restrict__ B,
                  float* __restrict__ C, const float* __restrict__ bias,
                  int M, int N, int K, int lda, int ldb, int ldc)
{
    __shared__ float As[8][128];
    __shared__ float Bs[8][128];
    const int tid = threadIdx.x;
    const int tx = tid & 15, ty = tid >> 4;
    const int n0 = blockIdx.x * 128, m0 = blockIdx.y * 128;
    float acc[8][8] = {};

    for (int kb = 0; kb < K; kb += 8) {
        {
            int r = tid >> 1, c = (tid & 1) * 4;
            float4 v = *(const float4*)(A + (long)(m0 + r) * lda + kb + c);
            As[c + 0][r] = v.x; As[c + 1][r] = v.y;
            As[c + 2][r] = v.z; As[c + 3][r] = v.w;
        }
        {
            int r = tid >> 5, c = (tid & 31) * 4;
            *(float4*)&Bs[r][c] = *(const float4*)(B + (long)(kb + r) * ldb + n0 + c);
        }
        __syncthreads();
        #pragma unroll
        for (int kk = 0; kk < 8; ++kk) {
            float a[8], b[8];
            *(float4*)&a[0] = *(const float4*)&As[kk][ty * 8];
            *(float4*)&a[4] = *(const float4*)&As[kk][ty * 8 + 4];
            *(float4*)&b[0] = *(const float4*)&Bs[kk][tx * 8];
            *(float4*)&b[4] = *(const float4*)&Bs[kk][tx * 8 + 4];
            #pragma unroll
            for (int i = 0; i < 8; ++i)
                #pragma unroll
                for (int j = 0; j < 8; ++j)
                    acc[i][j] = fmaf(a[i], b[j], acc[i][j]);
        }
        __syncthreads();
    }

    #pragma unroll
    for (int i = 0; i < 8; ++i) {
        int gm = m0 + ty * 8 + i;
        #pragma unroll
        for (int j = 0; j < 8; j += 4) {
            int gn = n0 + tx * 8 + j;
            float4 v = {acc[i][j], acc[i][j+1], acc[i][j+2], acc[i][j+3]};
            if (bias != nullptr) {
                v.x += bias[gn]; v.y += bias[gn + 1];
                v.z += bias[gn + 2]; v.w += bias[gn + 3];
            }
            *(float4*)(C + (long)gm * ldc + gn) = v;
        }
    }
}

// ---------------------------------------------------------------------------
// bf16 MFMA GEMM (plain): chaos-safe hW GEMM only.
// ---------------------------------------------------------------------------
__global__ __launch_bounds__(256)
void mfma_gemm(const unsigned short* __restrict__ A,
               const unsigned short* __restrict__ Bt,
               float* __restrict__ C, const float* __restrict__ bias,
               int M, int N, int K, int lda, int ldb, int ldc, int kChunk)
{
    __shared__ unsigned short As[128][40];
    __shared__ unsigned short Bs[128][40];
    const int tid  = threadIdx.x;
    const int lane = tid & 63;
    const int wv   = tid >> 6;
    const int wr   = wv >> 1, wc = wv & 1;
    const int n0 = blockIdx.x * 128;
    const int m0 = blockIdx.y * 128;
    const int z  = blockIdx.z;
    const int k0 = z * kChunk;
    const int k1 = min(K, k0 + kChunk);

    const int srow = tid >> 2;
    const int skoff = (tid & 3) * 8;

    f32x4 acc[4][4] = {};

    for (int kb = k0; kb < k1; kb += 32) {
        #pragma unroll
        for (int p = 0; p < 2; ++p) {
            int row = p * 64 + srow;
            u16x8 va = *(const u16x8*)(A + (long)(m0 + row) * lda + kb + skoff);
            *(u16x8*)&As[row][skoff] = va;
            int gb = n0 + row;
            u16x8 vb = {0, 0, 0, 0, 0, 0, 0, 0};
            if (gb < N) vb = *(const u16x8*)(Bt + (long)gb * ldb + kb + skoff);
            *(u16x8*)&Bs[row][skoff] = vb;
        }
        __syncthreads();
        bf16x8 af[4], bfr[4];
        #pragma unroll
        for (int fm = 0; fm < 4; ++fm)
            af[fm] = *(const bf16x8*)&As[wr * 64 + fm * 16 + (lane & 15)][(lane >> 4) * 8];
        #pragma unroll
        for (int fn = 0; fn < 4; ++fn)
            bfr[fn] = *(const bf16x8*)&Bs[wc * 64 + fn * 16 + (lane & 15)][(lane >> 4) * 8];
        #pragma unroll
        for (int fm = 0; fm < 4; ++fm)
            #pragma unroll
            for (int fn = 0; fn < 4; ++fn)
                acc[fm][fn] = __builtin_amdgcn_mfma_f32_16x16x32_bf16(
                    af[fm], bfr[fn], acc[fm][fn], 0, 0, 0);
        __syncthreads();
    }

    const bool split = (gridDim.z > 1);
    #pragma unroll
    for (int fm = 0; fm < 4; ++fm) {
        int row = m0 + wr * 64 + fm * 16 + ((lane >> 4) << 2);
        #pragma unroll
        for (int fn = 0; fn < 4; ++fn) {
            int col = n0 + wc * 64 + fn * 16 + (lane & 15);
            if (col >= N) continue;
            f32x4 v = acc[fm][fn];
            #pragma unroll
            for (int r = 0; r < 4; ++r) {
                float o = v[r];
                if (bias != nullptr && z == 0) o += bias[col];
                if (split) atomicAdd(&C[(long)(row + r) * ldc + col], o);
                else       C[(long)(row + r) * ldc + col] = o;
            }
        }
    }
}

// ---------------------------------------------------------------------------
// cast kernels
// ---------------------------------------------------------------------------
__global__ void castbf(const float* __restrict__ in, unsigned short* __restrict__ out,
                       long n) {
    long stride = (long)gridDim.x * blockDim.x * 4;
    for (long j = ((long)blockIdx.x * blockDim.x + threadIdx.x) * 4; j < n; j += stride) {
        float4 v = *(const float4*)(in + j);
        ushort4 o;
        o.x = f2bf(v.x); o.y = f2bf(v.y); o.z = f2bf(v.z); o.w = f2bf(v.w);
        *(ushort4*)(out + j) = o;
    }
}
__global__ void cast_strided(const float* __restrict__ in, unsigned short* __restrict__ out,
                             int cols, long ldin, long off) {
    const int r = blockIdx.y;
    int c = (blockIdx.x * blockDim.x + threadIdx.x) * 4;
    if (c < cols) {
        float4 v = *(const float4*)(in + (long)r * ldin + off + c);
        ushort4 o;
        o.x = f2bf(v.x); o.y = f2bf(v.y); o.z = f2bf(v.z); o.w = f2bf(v.w);
        *(ushort4*)(out + (long)r * cols + c) = o;
    }
}

// ---------------------------------------------------------------------------
// small utility kernels
// ---------------------------------------------------------------------------
__global__ void zero_f32(float* p, long n) {
    for (long i = (long)blockIdx.x * blockDim.x + threadIdx.x; i < n;
         i += (long)gridDim.x * blockDim.x) p[i] = 0.f;
}
__global__ void zero_i32(int* p, long n) {
    for (long i = (long)blockIdx.x * blockDim.x + threadIdx.x; i < n;
         i += (long)gridDim.x * blockDim.x) p[i] = 0;
}
// fused small-prep: b0s, b1s, bc2, sW in one launch
__global__ __launch_bounds__(256)
void prep_kernel(const float* __restrict__ bih0, const float* __restrict__ bhh0,
                 const float* __restrict__ bih1, const float* __restrict__ bhh1,
                 const float* __restrict__ b_conv, const float* __restrict__ c0,
                 const float* __restrict__ W_alm,
                 float* b0s, float* b1s, float* bc2, float* sW) {
    const int b = blockIdx.x, t = threadIdx.x;
    if (b < 8) {
        int i = b * 256 + t;
        b0s[i] = bih0[i] + bhh0[i];
        b1s[i] = bih1[i] + bhh1[i];
    } else if (b == 8) {
        bc2[t] = b_conv[t];
        bc2[t + 256] = 0.f;
    } else {
        if (t < 2 * NPG_) {
            int l = t / NPG_, p = t % NPG_;
            float s = 0.f;
            for (int k = 0; k < R_LSTM; ++k)
                s += c0[l * R_LSTM + k] * W_alm[(long)p * 51712 + k];
            sW[l * NPG_ + p] = s;
        }
    }
}

// CSR build
__global__ void hist_kernel(const int* __restrict__ key, int* counts, int E) {
    int i = blockIdx.x * blockDim.x + threadIdx.x;
    if (i < E) atomicAdd(&counts[key[i]], 1);
}
__global__ __launch_bounds__(256)
void scan_chunk(const int* __restrict__ counts, int* __restrict__ rowptr,
                int* __restrict__ tops, int n) {
    __shared__ int buf[256];
    const int tid = threadIdx.x;
    int i = blockIdx.x * 256 + tid;
    int v = (i < n) ? counts[i] : 0;
    buf[tid] = v;
    __syncthreads();
    for (int off = 1; off < 256; off <<= 1) {
        int add = (tid >= off) ? buf[tid - off] : 0;
        __syncthreads();
        buf[tid] += add;
        __syncthreads();
    }
    if (i < n) rowptr[i + 1] = buf[tid];
    if (tid == 255) tops[blockIdx.x] = buf[255];
}
__global__ __launch_bounds__(128)
void scan_tops(int* tops, int nt) {
    __shared__ int b[128];
    int tid = threadIdx.x;
    int v = (tid < nt) ? tops[tid] : 0;
    b[tid] = v;
    __syncthreads();
    for (int off = 1; off < 128; off <<= 1) {
        int add = (tid >= off) ? b[tid - off] : 0;
        __syncthreads();
        b[tid] += add;
        __syncthreads();
    }
    if (tid < nt) tops[tid] = b[tid] - v;
}
__global__ void scan_fixup(const int* __restrict__ counts, int* __restrict__ rowptr,
                           int* __restrict__ cursor, const int* __restrict__ tops, int n) {
    int i = blockIdx.x * blockDim.x + threadIdx.x;
    if (i < n) {
        int r = rowptr[i + 1] + tops[i >> 8];
        rowptr[i + 1] = r;
        cursor[i] = r - counts[i];
        if (i == 0) rowptr[0] = 0;
    }
}
__global__ void scatter_kernel(const int* __restrict__ key, const int* __restrict__ val,
                               int* cursor, int* sorted, int E) {
    int i = blockIdx.x * blockDim.x + threadIdx.x;
    if (i < E) {
        int pos = atomicAdd(&cursor[key[i]], 1);
        sorted[pos] = val[i];
    }
}
__global__ __launch_bounds__(256)
void agg_conv_kernel(const float* __restrict__ xrn,
                     const int* __restrict__ rowptr, const int* __restrict__ sorted,
                     float* __restrict__ xc, int outOff) {
    const int n = blockIdx.x, tid = threadIdx.x;
    float acc = xrn[(long)n * 512 + tid];
    const int s = rowptr[n], e = rowptr[n + 1];
    for (int t = s; t < e; ++t)
        acc += xrn[(long)sorted[t] * 512 + 256 + tid];
    xc[(long)n * 512 + outOff + tid] = fmaxf(acc, 0.f);
}

__global__ __launch_bounds__(512)
void colstat_kernel(const float* __restrict__ h1, float* colsum, float* colsq) {
    const int c = threadIdx.x;
    const int r0 = blockIdx.x * 128;
    float s = 0.f, s2 = 0.f;
    for (int r = 0; r < 128; ++r) {
        float v = h1[(long)(r0 + r) * D_MLP + c];
        s += v; s2 += v * v;
    }
    atomicAdd(&colsum[c], s);
    atomicAdd(&colsq[c], s2);
}
__global__ void finalize_stats(const float* colsum, const float* colsq,
                               const float* gamma, const float* beta,
                               float* scalev, float* shiftv) {
    int c = threadIdx.x;
    float m  = colsum[c] * (1.f / N_NODES);
    float vr = colsq[c] * (1.f / N_NODES) - m * m;
    float g  = gamma[c] * rsqrtf(vr + 1e-5f);
    scalev[c] = g;
    shiftv[c] = beta[c] - m * g;
}
__global__ __launch_bounds__(512)
void fused_norm_pool(const float* __restrict__ h1, const float* __restrict__ sc,
                     const float* __restrict__ sh, float* __restrict__ P) {
    const int b = blockIdx.x, c = threadIdx.x;
    const float scv = sc[c], shv = sh[c];
    float s = 0.f;
    for (int i = 0; i < NPG_; ++i) {
        float v = h1[(long)(b * NPG_ + i) * D_MLP + c];
        s += fmaxf(fmaf(v, scv, shv), 0.f);
    }
    P[b * D_MLP + c] = s * (1.f / NPG_);
}
__global__ __launch_bounds__(128)
void alpha_kernel(const float* __restrict__ sW, const float* __restrict__ hW,
                  const float* __restrict__ b_alm, float* __restrict__ alpha) {
    const int lb = blockIdx.x;
    const int l = lb >> 8, b = lb & 255;
    const int p = threadIdx.x;
    __shared__ float red[128];
    float v = 0.f;
    if (p < NPG_) v = sW[l * NPG_ + p] + hW[b * NPG_ + p] + b_alm[p];
    red[p] = v;
    __syncthreads();
    for (int s = 64; s > 0; s >>= 1) {
        if (p < s) red[p] += red[p + s];
        __syncthreads();
    }
    float inv = 1.f / red[0];
    if (p < NPG_) alpha[lb * NPG_ + p] = v * inv;
}
__global__ __launch_bounds__(512)
void newc_kernel(const float* __restrict__ alpha, const float* __restrict__ xc,
                 float* new_c) {
    const int l = blockIdx.y, chunk = blockIdx.x, c = threadIdx.x;
    const int r0 = chunk * 800;
    float acc = 0.f;
    for (int r = r0; r < r0 + 800; ++r)
        acc += alpha[l * N_NODES + r] * xc[(long)r * D_MLP + c];
    atomicAdd(&new_c[l * D_MLP + c], acc);
}

// ---------------------------------------------------------------------------
// Persistent fused LSTM + preds kernel.
// Blocks 0..31:  LSTM layer 0 (R7 structure: aggregated 64B h-store by w0).
// Blocks 32..63: LSTM layer 1.
// Blocks 64..313: preds consumers — poll h1st row t+1, f32 GEMV into out[t].
//   Consumer-only (no co-residency requirement; bounded spins terminate).
// ---------------------------------------------------------------------------
#define CANARY 0x7FC00000u
#define SPIN_MAX 20000

__device__ __forceinline__ unsigned coh_load_u(const unsigned* p) {
    return __hip_atomic_load(p, __ATOMIC_RELAXED, __HIP_MEMORY_SCOPE_AGENT);
}
__device__ __forceinline__ void coh_store_f(float* p, float v) {
    __hip_atomic_store(p, v, __ATOMIC_RELAXED, __HIP_MEMORY_SCOPE_AGENT);
}

__global__ void lstm_init_kernel(const float* __restrict__ h0,
                                 float* h0buf, float* h1buf) {
    int i = blockIdx.x * blockDim.x + threadIdx.x;
    if (i < 512) { h0buf[i] = h0[i]; h1buf[i] = h0[512 + i]; }
    for (int j = 512 + i; j < 257 * 512; j += gridDim.x * blockDim.x) {
        ((unsigned*)h0buf)[j] = CANARY;
        ((unsigned*)h1buf)[j] = CANARY;
    }
}

__global__ __launch_bounds__(512)
void lstm_kernel(const float* __restrict__ inp0, const float* __restrict__ Whh0,
                 const float* __restrict__ Wih1, const float* __restrict__ Whh1,
                 const float* __restrict__ b1s, const float* __restrict__ new_c,
                 float* h0buf, float* h1buf,
                 const float* __restrict__ W_fc, const float* __restrict__ b_fc,
                 float* __restrict__ out)
{
    const int tid  = threadIdx.x;
    const int lane = tid & 63;
    const int w    = tid >> 6;
    const int blk  = blockIdx.x;

    __shared__ float partial[2][8][64];
    __shared__ float hlds[512];
    __shared__ float pred_part[4][128];

    if (blk < 32) {
        const int base  = blk * 16;
        const int gate  = lane >> 4;
        const int hid   = lane & 15;
        const int rowg  = gate * 512 + base + hid;
        float wr[64];
        {
            const float4* wp = (const float4*)(Whh0 + (long)rowg * 512 + w * 64);
            #pragma unroll
            for (int i = 0; i < 16; ++i) {
                float4 v = wp[i];
                wr[4*i] = v.x; wr[4*i+1] = v.y; wr[4*i+2] = v.z; wr[4*i+3] = v.w;
            }
        }
        float c = (w == 0 && lane < 16) ? new_c[base + lane] : 0.f;
        const unsigned* src = (const unsigned*)h0buf + w * 64 + lane;
        for (int t = 0; t < 256; ++t) {
            float ipv = (w == 0) ? inp0[t * 2048 + rowg] : 0.f;
            unsigned hu; int guard = 0;
            for (;;) {
                hu = coh_load_u(src + (long)t * 512);
                if (!__any(hu == CANARY)) break;
                if (++guard > SPIN_MAX) break;
                if (guard > 32) __builtin_amdgcn_s_sleep(1);
            }
            float hv = __uint_as_float(hu);
            float acc = 0.f;
            #pragma unroll
            for (int j = 0; j < 64; ++j)
                acc = fmaf(wr[j], __shfl(hv, j), acc);
            partial[t & 1][w][lane] = acc;
            __syncthreads();
            if (w == 0) {
                float g = ipv;
                #pragma unroll
                for (int ww = 0; ww < 8; ++ww) g += partial[t & 1][ww][lane];
                float a = (gate == 2) ? tanhf(g) : 1.f / (1.f + expf(-g));
                float fv = __shfl(a, lane + 16);
                float gv = __shfl(a, lane + 32);
                float ov = __shfl(a, lane + 48);
                if (lane < 16) {
                    c = fv * c + a * gv;
                    float h = ov * tanhf(c);
                    coh_store_f(h0buf + (long)(t + 1) * 512 + base + lane, h);
                }
            }
        }
    } else if (blk < 64) {
        const int base  = (blk - 32) * 16;
        const int gate  = lane >> 4;
        const int hid   = lane & 15;
        const int rowg  = gate * 512 + base + hid;
        const float* Wsel = (w < 4) ? Wih1 : Whh1;
        const int koff = (w & 3) * 128;
        float wrA[64], wrB[64];
        {
            const float4* wp = (const float4*)(Wsel + (long)rowg * 512 + koff);
            #pragma unroll
            for (int i = 0; i < 16; ++i) {
                float4 v = wp[i];
                wrA[4*i] = v.x; wrA[4*i+1] = v.y; wrA[4*i+2] = v.z; wrA[4*i+3] = v.w;
            }
            #pragma unroll
            for (int i = 0; i < 16; ++i) {
                float4 v = wp[16 + i];
                wrB[4*i] = v.x; wrB[4*i+1] = v.y; wrB[4*i+2] = v.z; wrB[4*i+3] = v.w;
            }
        }
        float bsum = (w == 0) ? b1s[rowg] : 0.f;
        float c = (w == 0 && lane < 16) ? new_c[512 + base + lane] : 0.f;
        for (int t = 0; t < 256; ++t) {
            const unsigned* xsrc = (w < 4)
                ? (const unsigned*)h0buf + (long)(t + 1) * 512 + koff
                : (const unsigned*)h1buf + (long)t * 512 + koff;
            unsigned hu0, hu1; int guard = 0;
            for (;;) {
                hu0 = coh_load_u(xsrc + lane);
                hu1 = coh_load_u(xsrc + 64 + lane);
                if (!__any((hu0 == CANARY) || (hu1 == CANARY))) break;
                if (++guard > SPIN_MAX) break;
                if (guard > 32) __builtin_amdgcn_s_sleep(1);
            }
            float hv0 = __uint_as_float(hu0), hv1 = __uint_as_float(hu1);
            float acc = 0.f;
            #pragma unroll
            for (int j = 0; j < 64; ++j)
                acc = fmaf(wrA[j], __shfl(hv0, j), acc);
            #pragma unroll
            for (int j = 0; j < 64; ++j)
                acc = fmaf(wrB[j], __shfl(hv1, j), acc);
            partial[t & 1][w][lane] = acc;
            __syncthreads();
            if (w == 0) {
                float g = bsum;
                #pragma unroll
                for (int ww = 0; ww < 8; ++ww) g += partial[t & 1][ww][lane];
                float a = (gate == 2) ? tanhf(g) : 1.f / (1.f + expf(-g));
                float fv = __shfl(a, lane + 16);
                float gv = __shfl(a, lane + 32);
                float ov = __shfl(a, lane + 48);
                if (lane < 16) {
                    c = fv * c + a * gv;
                    float h = ov * tanhf(c);
                    coh_store_f(h1buf + (long)(t + 1) * 512 + base + lane, h);
                }
            }
        }
    } else {
        // ---- preds consumer blocks: out[t, c0:c0+128] = h1(t) @ W_fc + b_fc
        const int pb  = blk - 64;            // 0..249
        const int c0  = pb * 128;
        const int col = tid & 127;
        const int q   = tid >> 7;            // k-quarter 0..3
        float wr[128];
        #pragma unroll 16
        for (int j = 0; j < 128; ++j)
            wr[j] = W_fc[(long)(q * 128 + j) * V_OUT + c0 + col];
        const float bv = b_fc[c0 + col];     // valid for tid<128 finalizers
        for (int t = 0; t < 256; ++t) {
            if (w == 0) {
                const unsigned* src = (const unsigned*)h1buf + (long)(t + 1) * 512 + lane * 8;
                unsigned v[8]; int guard = 0;
                for (;;) {
                    bool bad = false;
                    #pragma unroll
                    for (int i = 0; i < 8; ++i) {
                        v[i] = coh_load_u(src + i);
                        bad = bad || (v[i] == CANARY);
                    }
                    if (!__any(bad)) break;
                    if (++guard > SPIN_MAX) break;
                    if (guard > 32) __builtin_amdgcn_s_sleep(1);
                }
                #pragma unroll
                for (int i = 0; i < 8; ++i) hlds[lane * 8 + i] = __uint_as_float(v[i]);
            }
            __syncthreads();
            float acc = 0.f;
            const f32x4* hp = (const f32x4*)&hlds[q * 128];
            #pragma unroll
            for (int j4 = 0; j4 < 32; ++j4) {
                f32x4 hv = hp[j4];
                acc = fmaf(wr[4*j4 + 0], hv.x, acc);
                acc = fmaf(wr[4*j4 + 1], hv.y, acc);
                acc = fmaf(wr[4*j4 + 2], hv.z, acc);
                acc = fmaf(wr[4*j4 + 3], hv.w, acc);
            }
            pred_part[q][col] = acc;
            __syncthreads();
            if (tid < 128) {
                float s = pred_part[0][tid] + pred_part[1][tid]
                        + pred_part[2][tid] + pred_part[3][tid] + bv;
                out[(long)t * V_OUT + c0 + tid] = s;
            }
        }
    }
}

// ---------------------------------------------------------------------------
extern "C" void kernel_launch(void* const* d_in, const int* in_sizes, int n_in,
                              void* d_out, int out_size, void* d_ws, size_t ws_size,
                              hipStream_t stream)
{
    const float* x      = (const float*)d_in[0];
    const int*   ei     = (const int*)d_in[1];
    const float* h0     = (const float*)d_in[4];
    const float* c0     = (const float*)d_in[5];
    const float* W_gnn  = (const float*)d_in[6];
    const float* W_root = (const float*)d_in[7];
    const float* W_nbr  = (const float*)d_in[8];
    const float* b_conv = (const float*)d_in[9];
    const float* W1     = (const float*)d_in[10];
    const float* b1     = (const float*)d_in[11];
    const float* gamma  = (const float*)d_in[12];
    const float* beta   = (const float*)d_in[13];
    const float* W2     = (const float*)d_in[14];
    const float* b2     = (const float*)d_in[15];
    const float* W_alm  = (const float*)d_in[16];
    const float* b_alm  = (const float*)d_in[17];
    const float* Wih0   = (const float*)d_in[18];
    const float* Whh0   = (const float*)d_in[19];
    const float* bih0   = (const float*)d_in[20];
    const float* bhh0   = (const float*)d_in[21];
    const float* Wih1   = (const float*)d_in[22];
    const float* Whh1   = (const float*)d_in[23];
    const float* bih1   = (const float*)d_in[24];
    const float* bhh1   = (const float*)d_in[25];
    const float* W_fc   = (const float*)d_in[26];
    const float* b_fc   = (const float*)d_in[27];
    float* out = (float*)d_out;
    float* ws  = (float*)d_ws;

    const int* ei0 = ei;
    const int* ei1 = ei + E_EDGE;

    // ---- workspace layout (float offsets) ----
    float* xrn = ws;
    float* h1m = ws;
    unsigned short* Walmb = (unsigned short*)(ws + 8500000L);    // 100x51200 bf16
    float* xc = ws + 13107200L;                                  // 25600x512 f32
    long o = 26214400L;
    float* Wc    = ws + o; o += 65536;
    int*   counts= (int*)(ws + o); o += 25600;
    int*   rowptr= (int*)(ws + o); o += 25601;
    int*   cursor= (int*)(ws + o); o += 25600;
    int*   sorted= (int*)(ws + o); o += 409600;
    int*   tops  = (int*)(ws + o); o += 128;
    float* colsum= ws + o; o += 512;
    float* colsq = ws + o; o += 512;
    float* scalev= ws + o; o += 512;
    float* shiftv= ws + o; o += 512;
    float* P     = ws + o; o += 131072;
    float* x_g   = ws + o; o += 131072;
    float* hW    = ws + o; o += 25600;
    float* sW    = ws + o; o += 200;
    float* alphav= ws + o; o += 51200;
    float* newc  = ws + o; o += 1024;
    float* b0s   = ws + o; o += 2048;
    float* b1s   = ws + o; o += 2048;
    float* bc2   = ws + o; o += 512;
    unsigned short* xcb = (unsigned short*)(ws + o);
    float* inp0  = ws + o;            // overlays xcb (xcb dead before inp0 write)
    float* h0st  = ws + o + 524288;
    float* h1st  = ws + o + 655872;
    o += 6553600;

    // 0. fused prep (b0s, b1s, bc2, sW)
    prep_kernel<<<dim3(10), 256, 0, stream>>>(bih0, bhh0, bih1, bhh1, b_conv, c0,
                                              W_alm, b0s, b1s, bc2, sW);
    // 1. conv weight folding
    gemm_tile<false><<<dim3(4, 2, 1), 256, 0, stream>>>(W_gnn, W_root, Wc, nullptr,
        128, 256, 256, 256, 256, 512, 256);
    gemm_tile<false><<<dim3(4, 2, 1), 256, 0, stream>>>(W_gnn, W_nbr, Wc + 256, nullptr,
        128, 256, 256, 256, 256, 512, 256);
    // 2. fused conv GEMM (f32): xrn = x @ Wc + bc2
    gemm_f32_big<<<dim3(4, 200), 256, 0, stream>>>(x, Wc, xrn, bc2,
        N_NODES, 512, 128, 128, 512, 512);
    // 3. forward conv: CSR by dst
    zero_i32<<<dim3(100), 256, 0, stream>>>(counts, 25600);
    hist_kernel<<<dim3(1600), 256, 0, stream>>>(ei1, counts, E_EDGE);
    scan_chunk<<<dim3(100), 256, 0, stream>>>(counts, rowptr, tops, 25600);
    scan_tops<<<dim3(1), 128, 0, stream>>>(tops, 100);
    scan_fixup<<<dim3(100), 256, 0, stream>>>(counts, rowptr, cursor, tops, 25600);
    scatter_kernel<<<dim3(1600), 256, 0, stream>>>(ei1, ei0, cursor, sorted, E_EDGE);
    agg_conv_kernel<<<dim3(25600), 256, 0, stream>>>(xrn, rowptr, sorted, xc, 0);
    // 4. backward conv: CSR by src
    zero_i32<<<dim3(100), 256, 0, stream>>>(counts, 25600);
    hist_kernel<<<dim3(1600), 256, 0, stream>>>(ei0, counts, E_EDGE);
    scan_chunk<<<dim3(100), 256, 0, stream>>>(counts, rowptr, tops, 25600);
    scan_tops<<<dim3(1), 128, 0, stream>>>(tops, 100);
    scan_fixup<<<dim3(100), 256, 0, stream>>>(counts, rowptr, cursor, tops, 25600);
    scatter_kernel<<<dim3(1600), 256, 0, stream>>>(ei0, ei1, cursor, sorted, E_EDGE);
    agg_conv_kernel<<<dim3(25600), 256, 0, stream>>>(xrn, rowptr, sorted, xc, 256);
    // 5. h1 = xc@W1 + b1 (exact f32)
    gemm_f32_big<<<dim3(4, 200), 256, 0, stream>>>(xc, W1, h1m, b1,
        N_NODES, 512, 512, 512, 512, 512);
    // 6. per-column layernorm stats
    zero_f32<<<dim3(4), 256, 0, stream>>>(colsum, 1024);
    colstat_kernel<<<dim3(200), 512, 0, stream>>>(h1m, colsum, colsq);
    finalize_stats<<<dim3(1), 512, 0, stream>>>(colsum, colsq, gamma, beta, scalev, shiftv);
    // 7. fused norm+relu+pool, then x_g = P@W2 + b2 (f32)
    fused_norm_pool<<<dim3(256), 512, 0, stream>>>(h1m, scalev, shiftv, P);
    gemm_tile<false><<<dim3(8, 4, 1), 256, 0, stream>>>(P, W2, x_g, b2,
        256, 512, 512, 512, 512, 512, 512);
    // h1m dead: overlay cast for hW
    cast_strided<<<dim3(50, 100), 256, 0, stream>>>(W_alm, Walmb, 51200, 51712L, 512L);
    castbf<<<dim3(1024), 256, 0, stream>>>(xc, xcb, 13107200L);
    // 8. hW = xc_flat(256x51200) @ Wh^T -- bf16 MFMA split-K (chaos-safe)
    zero_f32<<<dim3(25), 256, 0, stream>>>(hW, 25600);
    mfma_gemm<<<dim3(1, 2, 32), 256, 0, stream>>>(xcb, Walmb, hW, nullptr,
        256, 100, 51200, 51200, 51200, 100, 1600);
    // 9. alpha and new_c (f32 xc)
    alpha_kernel<<<dim3(512), 128, 0, stream>>>(sW, hW, b_alm, alphav);
    zero_f32<<<dim3(1), 256, 0, stream>>>(newc, 1024);
    newc_kernel<<<dim3(32, 2), 512, 0, stream>>>(alphav, xc, newc);
    // 10. LSTM input projection (f32; xcb dead -> inp0 overlays)
    gemm_tile<true><<<dim3(32, 4, 1), 256, 0, stream>>>(x_g, Wih0, inp0, b0s,
        256, 2048, 512, 512, 512, 2048, 512);
    // 11. fused persistent LSTM (64 blocks) + preds consumers (250 blocks)
    lstm_init_kernel<<<dim3(64), 512, 0, stream>>>(h0, h0st, h1st);
    lstm_kernel<<<dim3(314), 512, 0, stream>>>(inp0, Whh0, Wih1, Whh1, b1s, newc,
                                               h0st, h1st, W_fc, b_fc, out);
}

// Round 11
// 1894.155 us; speedup vs baseline: 2.3388x; 2.3388x over previous
//
#include <hip/hip_runtime.h>
#include <math.h>

#define N_NODES 25600
#define F_IN    128
#define H_GNN   256
#define D_MLP   512
#define E_EDGE  409600
#define B_GR    256
#define NPG_    100
#define R_LSTM  512
#define V_OUT   32000

typedef __bf16 bf16x8 __attribute__((ext_vector_type(8)));
typedef float  f32x4  __attribute__((ext_vector_type(4)));
typedef unsigned short u16x8 __attribute__((ext_vector_type(8)));

__device__ __forceinline__ unsigned short f2bf(float x) {
    unsigned u = __builtin_bit_cast(unsigned, x);
    unsigned r = (u + 0x7FFFu + ((u >> 16) & 1u)) >> 16;
    return (unsigned short)r;
}

// ---------------------------------------------------------------------------
// Generic f32 tiled GEMM — small GEMMs (weight folds, W2, inp0).
// ---------------------------------------------------------------------------
template<bool TRANSB>
__global__ __launch_bounds__(256)
void gemm_tile(const float* __restrict__ A, const float* __restrict__ B,
               float* __restrict__ C, const float* __restrict__ bias,
               int M, int N, int K, int lda, int ldb, int ldc, int kChunk)
{
    __shared__ float As[16][68];
    __shared__ float Bs[16][68];
    const int tid = threadIdx.x;
    const int n0 = blockIdx.x * 64;
    const int m0 = blockIdx.y * 64;
    const int z  = blockIdx.z;
    const int k0 = z * kChunk;
    const int k1 = min(K, k0 + kChunk);
    const int ty = tid >> 4, tx = tid & 15;
    float acc[4][4] = {};

    for (int kb = k0; kb < k1; kb += 16) {
        {
            const int r = tid >> 4, c = tid & 15;
            #pragma unroll
            for (int i = 0; i < 4; ++i) {
                int rr = r + i * 16;
                int gm = m0 + rr, gk = kb + c;
                As[c][rr] = (gm < M && gk < k1) ? A[gm * lda + gk] : 0.f;
            }
        }
        if (!TRANSB) {
            const int r = tid >> 6, c = tid & 63;
            #pragma unroll
            for (int i = 0; i < 4; ++i) {
                int rr = r + i * 4;
                int gk = kb + rr, gn = n0 + c;
                Bs[rr][c] = (gk < k1 && gn < N) ? B[gk * ldb + gn] : 0.f;
            }
        } else {
            const int r = tid & 15, c = tid >> 4;
            #pragma unroll
            for (int i = 0; i < 4; ++i) {
                int cc = c + i * 16;
                int gk = kb + r, gn = n0 + cc;
                Bs[r][cc] = (gk < k1 && gn < N) ? B[gn * ldb + gk] : 0.f;
            }
        }
        __syncthreads();
        #pragma unroll
        for (int kk = 0; kk < 16; ++kk) {
            float a[4], b[4];
            #pragma unroll
            for (int i = 0; i < 4; ++i) a[i] = As[kk][ty * 4 + i];
            #pragma unroll
            for (int j = 0; j < 4; ++j) b[j] = Bs[kk][tx * 4 + j];
            #pragma unroll
            for (int i = 0; i < 4; ++i)
                #pragma unroll
                for (int j = 0; j < 4; ++j)
                    acc[i][j] = fmaf(a[i], b[j], acc[i][j]);
        }
        __syncthreads();
    }

    const bool split = (gridDim.z > 1);
    #pragma unroll
    for (int i = 0; i < 4; ++i) {
        int gm = m0 + ty * 4 + i;
        if (gm >= M) continue;
        #pragma unroll
        for (int j = 0; j < 4; ++j) {
            int gn = n0 + tx * 4 + j;
            if (gn >= N) continue;
            float v = acc[i][j];
            if (bias != nullptr && z == 0) v += bias[gn];
            if (split) atomicAdd(&C[gm * ldc + gn], v);
            else       C[gm * ldc + gn] = v;
        }
    }
}

// ---------------------------------------------------------------------------
// Big-tile f32 GEMM: 128x128 tile, 8x8 micro-tile, exact f32.
// ---------------------------------------------------------------------------
__global__ __launch_bounds__(256)
void gemm_f32_big(const float* __restrict__ A, const float* __restrict__ B,
                  float* __restrict__ C, const float* __restrict__ bias,
                  int M, int N, int K, int lda, int ldb, int ldc)
{
    __shared__ float As[8][128];
    __shared__ float Bs[8][128];
    const int tid = threadIdx.x;
    const int tx = tid & 15, ty = tid >> 4;
    const int n0 = blockIdx.x * 128, m0 = blockIdx.y * 128;
    float acc[8][8] = {};

    for (int kb = 0; kb < K; kb += 8) {
        {
            int r = tid >> 1, c = (tid & 1) * 4;
            float4 v = *(const float4*)(A + (long)(m0 + r) * lda + kb + c);
            As[c + 0][r] = v.x; As[c + 1][r] = v.y;
            As[c + 2][r] = v.z; As[c + 3][r] = v.w;
        }
        {
            int r = tid >> 5, c = (tid & 31) * 4;
            *(float4*)&Bs[r][c] = *(const float4*)(B + (long)(kb + r) * ldb + n0 + c);
        }
        __syncthreads();
        #pragma unroll
        for (int kk = 0; kk < 8; ++kk) {
            float a[8], b[8];
            *(float4*)&a[0] = *(const float4*)&As[kk][ty * 8];
            *(float4*)&a[4] = *(const float4*)&As[kk][ty * 8 + 4];
            *(float4*)&b[0] = *(const float4*)&Bs[kk][tx * 8];
            *(float4*)&b[4] = *(const float4*)&Bs[kk][tx * 8 + 4];
            #pragma unroll
            for (int i = 0; i < 8; ++i)
                #pragma unroll
                for (int j = 0; j < 8; ++j)
                    acc[i][j] = fmaf(a[i], b[j], acc[i][j]);
        }
        __syncthreads();
    }

    #pragma unroll
    for (int i = 0; i < 8; ++i) {
        int gm = m0 + ty * 8 + i;
        #pragma unroll
        for (int j = 0; j < 8; j += 4) {
            int gn = n0 + tx * 8 + j;
            float4 v = {acc[i][j], acc[i][j+1], acc[i][j+2], acc[i][j+3]};
            if (bias != nullptr) {
                v.x += bias[gn]; v.y += bias[gn + 1];
                v.z += bias[gn + 2]; v.w += bias[gn + 3];
            }
            *(float4*)(C + (long)gm * ldc + gn) = v;
        }
    }
}

// ---------------------------------------------------------------------------
// bf16 MFMA GEMM (plain): chaos-safe GEMMs only (hW, preds).
// ---------------------------------------------------------------------------
__global__ __launch_bounds__(256)
void mfma_gemm(const unsigned short* __restrict__ A,
               const unsigned short* __restrict__ Bt,
               float* __restrict__ C, const float* __restrict__ bias,
               int M, int N, int K, int lda, int ldb, int ldc, int kChunk)
{
    __shared__ unsigned short As[128][40];
    __shared__ unsigned short Bs[128][40];
    const int tid  = threadIdx.x;
    const int lane = tid & 63;
    const int wv   = tid >> 6;
    const int wr   = wv >> 1, wc = wv & 1;
    const int n0 = blockIdx.x * 128;
    const int m0 = blockIdx.y * 128;
    const int z  = blockIdx.z;
    const int k0 = z * kChunk;
    const int k1 = min(K, k0 + kChunk);

    const int srow = tid >> 2;
    const int skoff = (tid & 3) * 8;

    f32x4 acc[4][4] = {};

    for (int kb = k0; kb < k1; kb += 32) {
        #pragma unroll
        for (int p = 0; p < 2; ++p) {
            int row = p * 64 + srow;
            u16x8 va = *(const u16x8*)(A + (long)(m0 + row) * lda + kb + skoff);
            *(u16x8*)&As[row][skoff] = va;
            int gb = n0 + row;
            u16x8 vb = {0, 0, 0, 0, 0, 0, 0, 0};
            if (gb < N) vb = *(const u16x8*)(Bt + (long)gb * ldb + kb + skoff);
            *(u16x8*)&Bs[row][skoff] = vb;
        }
        __syncthreads();
        bf16x8 af[4], bfr[4];
        #pragma unroll
        for (int fm = 0; fm < 4; ++fm)
            af[fm] = *(const bf16x8*)&As[wr * 64 + fm * 16 + (lane & 15)][(lane >> 4) * 8];
        #pragma unroll
        for (int fn = 0; fn < 4; ++fn)
            bfr[fn] = *(const bf16x8*)&Bs[wc * 64 + fn * 16 + (lane & 15)][(lane >> 4) * 8];
        #pragma unroll
        for (int fm = 0; fm < 4; ++fm)
            #pragma unroll
            for (int fn = 0; fn < 4; ++fn)
                acc[fm][fn] = __builtin_amdgcn_mfma_f32_16x16x32_bf16(
                    af[fm], bfr[fn], acc[fm][fn], 0, 0, 0);
        __syncthreads();
    }

    const bool split = (gridDim.z > 1);
    #pragma unroll
    for (int fm = 0; fm < 4; ++fm) {
        int row = m0 + wr * 64 + fm * 16 + ((lane >> 4) << 2);
        #pragma unroll
        for (int fn = 0; fn < 4; ++fn) {
            int col = n0 + wc * 64 + fn * 16 + (lane & 15);
            if (col >= N) continue;
            f32x4 v = acc[fm][fn];
            #pragma unroll
            for (int r = 0; r < 4; ++r) {
                float o = v[r];
                if (bias != nullptr && z == 0) o += bias[col];
                if (split) atomicAdd(&C[(long)(row + r) * ldc + col], o);
                else       C[(long)(row + r) * ldc + col] = o;
            }
        }
    }
}

// ---------------------------------------------------------------------------
// cast / transpose kernels
// ---------------------------------------------------------------------------
__global__ void castbf(const float* __restrict__ in, unsigned short* __restrict__ out,
                       long n) {
    long stride = (long)gridDim.x * blockDim.x * 4;
    for (long j = ((long)blockIdx.x * blockDim.x + threadIdx.x) * 4; j < n; j += stride) {
        float4 v = *(const float4*)(in + j);
        ushort4 o;
        o.x = f2bf(v.x); o.y = f2bf(v.y); o.z = f2bf(v.z); o.w = f2bf(v.w);
        *(ushort4*)(out + j) = o;
    }
}
__global__ void cast_strided(const float* __restrict__ in, unsigned short* __restrict__ out,
                             int cols, long ldin, long off) {
    const int r = blockIdx.y;
    int c = (blockIdx.x * blockDim.x + threadIdx.x) * 4;
    if (c < cols) {
        float4 v = *(const float4*)(in + (long)r * ldin + off + c);
        ushort4 o;
        o.x = f2bf(v.x); o.y = f2bf(v.y); o.z = f2bf(v.z); o.w = f2bf(v.w);
        *(ushort4*)(out + (long)r * cols + c) = o;
    }
}
__global__ __launch_bounds__(256)
void transcast(const float* __restrict__ in, unsigned short* __restrict__ out,
               int R, int C) {
    __shared__ unsigned short t[64][72];
    const int c0 = blockIdx.x * 64, r0 = blockIdx.y * 64;
    const int tid = threadIdx.x;
    const int rr = tid >> 2, cg = (tid & 3) * 16;
    #pragma unroll
    for (int i = 0; i < 4; ++i) {
        float4 v = *(const float4*)(in + (long)(r0 + rr) * C + c0 + cg + i * 4);
        t[cg + i * 4 + 0][rr] = f2bf(v.x);
        t[cg + i * 4 + 1][rr] = f2bf(v.y);
        t[cg + i * 4 + 2][rr] = f2bf(v.z);
        t[cg + i * 4 + 3][rr] = f2bf(v.w);
    }
    __syncthreads();
    const int cc = tid >> 2, kg = (tid & 3) * 16;
    #pragma unroll
    for (int i = 0; i < 2; ++i) {
        u16x8 v = *(const u16x8*)&t[cc][kg + i * 8];
        *(u16x8*)(out + (long)(c0 + cc) * R + r0 + kg + i * 8) = v;
    }
}

// ---------------------------------------------------------------------------
// small utility kernels
// ---------------------------------------------------------------------------
__global__ void zero_i32(int* p, long n) {
    for (long i = (long)blockIdx.x * blockDim.x + threadIdx.x; i < n;
         i += (long)gridDim.x * blockDim.x) p[i] = 0;
}
// fused small-prep: b0s, b1s, bc2, sW, and zero-init of colsum/colsq/newc/hW.
// grid = 111 blocks x 256.
__global__ __launch_bounds__(256)
void prep_kernel(const float* __restrict__ bih0, const float* __restrict__ bhh0,
                 const float* __restrict__ bih1, const float* __restrict__ bhh1,
                 const float* __restrict__ b_conv, const float* __restrict__ c0,
                 const float* __restrict__ W_alm,
                 float* b0s, float* b1s, float* bc2, float* sW,
                 float* colsum, float* colsq, float* newc, float* hW) {
    const int b = blockIdx.x, t = threadIdx.x;
    if (b < 8) {
        int i = b * 256 + t;
        b0s[i] = bih0[i] + bhh0[i];
        b1s[i] = bih1[i] + bhh1[i];
    } else if (b == 8) {
        bc2[t] = b_conv[t];
        bc2[t + 256] = 0.f;
    } else if (b == 9) {
        if (t < 2 * NPG_) {
            int l = t / NPG_, p = t % NPG_;
            float s = 0.f;
            for (int k = 0; k < R_LSTM; ++k)
                s += c0[l * R_LSTM + k] * W_alm[(long)p * 51712 + k];
            sW[l * NPG_ + p] = s;
        }
    } else if (b == 10) {
        for (int i = t; i < 512; i += 256) { colsum[i] = 0.f; colsq[i] = 0.f; }
        for (int i = t; i < 1024; i += 256) newc[i] = 0.f;
    } else {
        int i = (b - 11) * 256 + t;          // blocks 11..110 -> 25600
        if (i < 25600) hW[i] = 0.f;
    }
}

// ---- merged dual-CSR build (dst-keyed for fwd conv, src-keyed for bwd) ----
__global__ void hist2_kernel(const int* __restrict__ ei0, const int* __restrict__ ei1,
                             int* counts_d, int* counts_s, int E) {
    int i = blockIdx.x * blockDim.x + threadIdx.x;
    if (i < E) {
        atomicAdd(&counts_d[ei1[i]], 1);
        atomicAdd(&counts_s[ei0[i]], 1);
    }
}
__global__ __launch_bounds__(256)
void scan_chunk2(const int* __restrict__ counts_d, const int* __restrict__ counts_s,
                 int* rowptr_d, int* rowptr_s, int* tops_d, int* tops_s, int n) {
    __shared__ int buf[256];
    const int half = blockIdx.x >= 100;
    const int chunk = half ? blockIdx.x - 100 : blockIdx.x;
    const int* counts = half ? counts_s : counts_d;
    int* rowptr = half ? rowptr_s : rowptr_d;
    int* tops   = half ? tops_s   : tops_d;
    const int tid = threadIdx.x;
    int i = chunk * 256 + tid;
    int v = (i < n) ? counts[i] : 0;
    buf[tid] = v;
    __syncthreads();
    for (int off = 1; off < 256; off <<= 1) {
        int add = (tid >= off) ? buf[tid - off] : 0;
        __syncthreads();
        buf[tid] += add;
        __syncthreads();
    }
    if (i < n) rowptr[i + 1] = buf[tid];
    if (tid == 255) tops[chunk] = buf[255];
}
__global__ __launch_bounds__(128)
void scan_tops2(int* tops_d, int* tops_s, int nt) {
    __shared__ int b[128];
    int* tops = (blockIdx.x == 0) ? tops_d : tops_s;
    int tid = threadIdx.x;
    int v = (tid < nt) ? tops[tid] : 0;
    b[tid] = v;
    __syncthreads();
    for (int off = 1; off < 128; off <<= 1) {
        int add = (tid >= off) ? b[tid - off] : 0;
        __syncthreads();
        b[tid] += add;
        __syncthreads();
    }
    if (tid < nt) tops[tid] = b[tid] - v;
}
__global__ void scan_fixup2(const int* __restrict__ counts_d, const int* __restrict__ counts_s,
                            int* rowptr_d, int* rowptr_s,
                            int* cursor_d, int* cursor_s,
                            const int* __restrict__ tops_d, const int* __restrict__ tops_s,
                            int n) {
    const int half = blockIdx.x >= 100;
    const int chunk = half ? blockIdx.x - 100 : blockIdx.x;
    const int* counts = half ? counts_s : counts_d;
    const int* tops   = half ? tops_s   : tops_d;
    int* rowptr = half ? rowptr_s : rowptr_d;
    int* cursor = half ? cursor_s : cursor_d;
    int i = chunk * 256 + threadIdx.x;
    if (i < n) {
        int r = rowptr[i + 1] + tops[chunk];
        rowptr[i + 1] = r;
        cursor[i] = r - counts[i];
        if (i == 0) rowptr[0] = 0;
    }
}
__global__ void scatter2_kernel(const int* __restrict__ ei0, const int* __restrict__ ei1,
                                int* cursor_d, int* cursor_s,
                                int* sorted_d, int* sorted_s, int E) {
    int i = blockIdx.x * blockDim.x + threadIdx.x;
    if (i < E) {
        int s = ei0[i], d = ei1[i];
        int pd = atomicAdd(&cursor_d[d], 1);
        sorted_d[pd] = s;
        int ps = atomicAdd(&cursor_s[s], 1);
        sorted_s[ps] = d;
    }
}
// merged fwd+bwd aggregation + relu, emitting xc (f32) AND xcb (bf16).
// 512 threads: tid<256 -> fwd half (dst CSR, cols 0:256); else bwd (src CSR).
__global__ __launch_bounds__(512)
void agg_conv2(const float* __restrict__ xrn,
               const int* __restrict__ rowptr_d, const int* __restrict__ sorted_d,
               const int* __restrict__ rowptr_s, const int* __restrict__ sorted_s,
               float* __restrict__ xc, unsigned short* __restrict__ xcb) {
    const int n = blockIdx.x;
    const int tid = threadIdx.x;
    const int c = tid & 255;
    const bool bwd = tid >= 256;
    const int* rowptr = bwd ? rowptr_s : rowptr_d;
    const int* sorted = bwd ? sorted_s : sorted_d;
    float acc = xrn[(long)n * 512 + c];
    const int s = rowptr[n], e = rowptr[n + 1];
    for (int t = s; t < e; ++t)
        acc += xrn[(long)sorted[t] * 512 + 256 + c];
    float r = fmaxf(acc, 0.f);
    long idx = (long)n * 512 + (bwd ? 256 : 0) + c;
    xc[idx] = r;
    xcb[idx] = f2bf(r);
}

__global__ __launch_bounds__(512)
void colstat_kernel(const float* __restrict__ h1, float* colsum, float* colsq) {
    const int c = threadIdx.x;
    const int r0 = blockIdx.x * 128;
    float s = 0.f, s2 = 0.f;
    for (int r = 0; r < 128; ++r) {
        float v = h1[(long)(r0 + r) * D_MLP + c];
        s += v; s2 += v * v;
    }
    atomicAdd(&colsum[c], s);
    atomicAdd(&colsq[c], s2);
}
__global__ void finalize_stats(const float* colsum, const float* colsq,
                               const float* gamma, const float* beta,
                               float* scalev, float* shiftv) {
    int c = threadIdx.x;
    float m  = colsum[c] * (1.f / N_NODES);
    float vr = colsq[c] * (1.f / N_NODES) - m * m;
    float g  = gamma[c] * rsqrtf(vr + 1e-5f);
    scalev[c] = g;
    shiftv[c] = beta[c] - m * g;
}
__global__ __launch_bounds__(512)
void fused_norm_pool(const float* __restrict__ h1, const float* __restrict__ sc,
                     const float* __restrict__ sh, float* __restrict__ P) {
    const int b = blockIdx.x, c = threadIdx.x;
    const float scv = sc[c], shv = sh[c];
    float s = 0.f;
    for (int i = 0; i < NPG_; ++i) {
        float v = h1[(long)(b * NPG_ + i) * D_MLP + c];
        s += fmaxf(fmaf(v, scv, shv), 0.f);
    }
    P[b * D_MLP + c] = s * (1.f / NPG_);
}
__global__ __launch_bounds__(128)
void alpha_kernel(const float* __restrict__ sW, const float* __restrict__ hW,
                  const float* __restrict__ b_alm, float* __restrict__ alpha) {
    const int lb = blockIdx.x;
    const int l = lb >> 8, b = lb & 255;
    const int p = threadIdx.x;
    __shared__ float red[128];
    float v = 0.f;
    if (p < NPG_) v = sW[l * NPG_ + p] + hW[b * NPG_ + p] + b_alm[p];
    red[p] = v;
    __syncthreads();
    for (int s = 64; s > 0; s >>= 1) {
        if (p < s) red[p] += red[p + s];
        __syncthreads();
    }
    float inv = 1.f / red[0];
    if (p < NPG_) alpha[lb * NPG_ + p] = v * inv;
}
__global__ __launch_bounds__(512)
void newc_kernel(const float* __restrict__ alpha, const float* __restrict__ xc,
                 float* new_c) {
    const int l = blockIdx.y, chunk = blockIdx.x, c = threadIdx.x;
    const int r0 = chunk * 800;
    float acc = 0.f;
    for (int r = r0; r < r0 + 800; ++r)
        acc += alpha[l * N_NODES + r] * xc[(long)r * D_MLP + c];
    atomicAdd(&new_c[l * D_MLP + c], acc);
}

// ---------------------------------------------------------------------------
// Persistent 2-layer LSTM, canary sync, precise libm — the measured-856µs
// structure (R7): 64 blocks, aggregated 64B h-store by wave 0 only.
// Poll population kept minimal (R10 lesson: extra pollers saturate LLC).
// ---------------------------------------------------------------------------
#define CANARY 0x7FC00000u
#define SPIN_MAX 20000

__device__ __forceinline__ unsigned coh_load_u(const unsigned* p) {
    return __hip_atomic_load(p, __ATOMIC_RELAXED, __HIP_MEMORY_SCOPE_AGENT);
}
__device__ __forceinline__ void coh_store_f(float* p, float v) {
    __hip_atomic_store(p, v, __ATOMIC_RELAXED, __HIP_MEMORY_SCOPE_AGENT);
}

__global__ void lstm_init_kernel(const float* __restrict__ h0,
                                 float* h0buf, float* h1buf) {
    int i = blockIdx.x * blockDim.x + threadIdx.x;
    if (i < 512) { h0buf[i] = h0[i]; h1buf[i] = h0[512 + i]; }
    for (int j = 512 + i; j < 257 * 512; j += gridDim.x * blockDim.x) {
        ((unsigned*)h0buf)[j] = CANARY;
        ((unsigned*)h1buf)[j] = CANARY;
    }
}

__global__ __launch_bounds__(512)
void lstm_kernel(const float* __restrict__ inp0, const float* __restrict__ Whh0,
                 const float* __restrict__ Wih1, const float* __restrict__ Whh1,
                 const float* __restrict__ b1s, const float* __restrict__ new_c,
                 float* h0buf, float* h1buf)
{
    const int tid  = threadIdx.x;
    const int lane = tid & 63;
    const int w    = tid >> 6;
    const int blk  = blockIdx.x;
    const int layer = blk >> 5;
    const int base  = (blk & 31) * 16;
    const int gate  = lane >> 4;
    const int hid   = lane & 15;
    const int rowg  = gate * 512 + base + hid;

    __shared__ float partial[2][8][64];

    if (layer == 0) {
        float wr[64];
        {
            const float4* wp = (const float4*)(Whh0 + (long)rowg * 512 + w * 64);
            #pragma unroll
            for (int i = 0; i < 16; ++i) {
                float4 v = wp[i];
                wr[4*i] = v.x; wr[4*i+1] = v.y; wr[4*i+2] = v.z; wr[4*i+3] = v.w;
            }
        }
        float c = (w == 0 && lane < 16) ? new_c[base + lane] : 0.f;
        const unsigned* src = (const unsigned*)h0buf + w * 64 + lane;
        for (int t = 0; t < 256; ++t) {
            float ipv = (w == 0) ? inp0[t * 2048 + rowg] : 0.f;
            unsigned hu; int guard = 0;
            for (;;) {
                hu = coh_load_u(src + (long)t * 512);
                if (!__any(hu == CANARY)) break;
                if (++guard > SPIN_MAX) break;
                if (guard > 32) __builtin_amdgcn_s_sleep(1);
            }
            float hv = __uint_as_float(hu);
            float acc = 0.f;
            #pragma unroll
            for (int j = 0; j < 64; ++j)
                acc = fmaf(wr[j], __shfl(hv, j), acc);
            partial[t & 1][w][lane] = acc;
            __syncthreads();
            if (w == 0) {
                float g = ipv;
                #pragma unroll
                for (int ww = 0; ww < 8; ++ww) g += partial[t & 1][ww][lane];
                float a = (gate == 2) ? tanhf(g) : 1.f / (1.f + expf(-g));
                float fv = __shfl(a, lane + 16);
                float gv = __shfl(a, lane + 32);
                float ov = __shfl(a, lane + 48);
                if (lane < 16) {
                    c = fv * c + a * gv;
                    float h = ov * tanhf(c);
                    coh_store_f(h0buf + (long)(t + 1) * 512 + base + lane, h);
                }
            }
        }
    } else {
        const float* Wsel = (w < 4) ? Wih1 : Whh1;
        const int koff = (w & 3) * 128;
        float wrA[64], wrB[64];
        {
            const float4* wp = (const float4*)(Wsel + (long)rowg * 512 + koff);
            #pragma unroll
            for (int i = 0; i < 16; ++i) {
                float4 v = wp[i];
                wrA[4*i] = v.x; wrA[4*i+1] = v.y; wrA[4*i+2] = v.z; wrA[4*i+3] = v.w;
            }
            #pragma unroll
            for (int i = 0; i < 16; ++i) {
                float4 v = wp[16 + i];
                wrB[4*i] = v.x; wrB[4*i+1] = v.y; wrB[4*i+2] = v.z; wrB[4*i+3] = v.w;
            }
        }
        float bsum = (w == 0) ? b1s[rowg] : 0.f;
        float c = (w == 0 && lane < 16) ? new_c[512 + base + lane] : 0.f;
        for (int t = 0; t < 256; ++t) {
            const unsigned* xsrc = (w < 4)
                ? (const unsigned*)h0buf + (long)(t + 1) * 512 + koff
                : (const unsigned*)h1buf + (long)t * 512 + koff;
            unsigned hu0, hu1; int guard = 0;
            for (;;) {
                hu0 = coh_load_u(xsrc + lane);
                hu1 = coh_load_u(xsrc + 64 + lane);
                if (!__any((hu0 == CANARY) || (hu1 == CANARY))) break;
                if (++guard > SPIN_MAX) break;
                if (guard > 32) __builtin_amdgcn_s_sleep(1);
            }
            float hv0 = __uint_as_float(hu0), hv1 = __uint_as_float(hu1);
            float acc = 0.f;
            #pragma unroll
            for (int j = 0; j < 64; ++j)
                acc = fmaf(wrA[j], __shfl(hv0, j), acc);
            #pragma unroll
            for (int j = 0; j < 64; ++j)
                acc = fmaf(wrB[j], __shfl(hv1, j), acc);
            partial[t & 1][w][lane] = acc;
            __syncthreads();
            if (w == 0) {
                float g = bsum;
                #pragma unroll
                for (int ww = 0; ww < 8; ++ww) g += partial[t & 1][ww][lane];
                float a = (gate == 2) ? tanhf(g) : 1.f / (1.f + expf(-g));
                float fv = __shfl(a, lane + 16);
                float gv = __shfl(a, lane + 32);
                float ov = __shfl(a, lane + 48);
                if (lane < 16) {
                    c = fv * c + a * gv;
                    float h = ov * tanhf(c);
                    coh_store_f(h1buf + (long)(t + 1) * 512 + base + lane, h);
                }
            }
        }
    }
}

// ---------------------------------------------------------------------------
extern "C" void kernel_launch(void* const* d_in, const int* in_sizes, int n_in,
                              void* d_out, int out_size, void* d_ws, size_t ws_size,
                              hipStream_t stream)
{
    const float* x      = (const float*)d_in[0];
    const int*   ei     = (const int*)d_in[1];
    const float* h0     = (const float*)d_in[4];
    const float* c0     = (const float*)d_in[5];
    const float* W_gnn  = (const float*)d_in[6];
    const float* W_root = (const float*)d_in[7];
    const float* W_nbr  = (const float*)d_in[8];
    const float* b_conv = (const float*)d_in[9];
    const float* W1     = (const float*)d_in[10];
    const float* b1     = (const float*)d_in[11];
    const float* gamma  = (const float*)d_in[12];
    const float* beta   = (const float*)d_in[13];
    const float* W2     = (const float*)d_in[14];
    const float* b2     = (const float*)d_in[15];
    const float* W_alm  = (const float*)d_in[16];
    const float* b_alm  = (const float*)d_in[17];
    const float* Wih0   = (const float*)d_in[18];
    const float* Whh0   = (const float*)d_in[19];
    const float* bih0   = (const float*)d_in[20];
    const float* bhh0   = (const float*)d_in[21];
    const float* Wih1   = (const float*)d_in[22];
    const float* Whh1   = (const float*)d_in[23];
    const float* bih1   = (const float*)d_in[24];
    const float* bhh1   = (const float*)d_in[25];
    const float* W_fc   = (const float*)d_in[26];
    const float* b_fc   = (const float*)d_in[27];
    float* out = (float*)d_out;
    float* ws  = (float*)d_ws;

    const int* ei0 = ei;
    const int* ei1 = ei + E_EDGE;

    // ---- workspace layout (float offsets) ----
    float* xrn = ws;
    float* h1m = ws;
    unsigned short* Wfct  = (unsigned short*)ws;                 // 32000x512 bf16
    unsigned short* Walmb = (unsigned short*)(ws + 8500000L);    // 100x51200 bf16
    unsigned short* ob    = (unsigned short*)(ws + 11200000L);   // 256x512 bf16
    float* xc = ws + 13107200L;                                  // 25600x512 f32
    long o = 26214400L;
    float* Wc    = ws + o; o += 65536;
    int*   counts_d = (int*)(ws + o); o += 25600;
    int*   counts_s = (int*)(ws + o); o += 25600;
    int*   rowptr_d = (int*)(ws + o); o += 25601;
    int*   rowptr_s = (int*)(ws + o); o += 25601;
    int*   cursor_d = (int*)(ws + o); o += 25600;
    int*   cursor_s = (int*)(ws + o); o += 25600;
    int*   sorted_d = (int*)(ws + o); o += 409600;
    int*   sorted_s = (int*)(ws + o); o += 409600;
    int*   tops_d   = (int*)(ws + o); o += 128;
    int*   tops_s   = (int*)(ws + o); o += 128;
    float* colsum= ws + o; o += 512;
    float* colsq = ws + o; o += 512;
    float* scalev= ws + o; o += 512;
    float* shiftv= ws + o; o += 512;
    float* P     = ws + o; o += 131072;
    float* x_g   = ws + o; o += 131072;
    float* hW    = ws + o; o += 25600;
    float* sW    = ws + o; o += 200;
    float* alphav= ws + o; o += 51200;
    float* newc  = ws + o; o += 1024;
    float* b0s   = ws + o; o += 2048;
    float* b1s   = ws + o; o += 2048;
    float* bc2   = ws + o; o += 512;
    unsigned short* xcb = (unsigned short*)(ws + o);
    float* inp0  = ws + o;            // overlays xcb (xcb dead before inp0 write)
    float* h0st  = ws + o + 524288;
    float* h1st  = ws + o + 655872;
    o += 6553600;

    // 0. fused prep (b0s, b1s, bc2, sW + zero colsum/colsq/newc/hW)
    prep_kernel<<<dim3(111), 256, 0, stream>>>(bih0, bhh0, bih1, bhh1, b_conv, c0,
                                               W_alm, b0s, b1s, bc2, sW,
                                               colsum, colsq, newc, hW);
    // 1. conv weight folding
    gemm_tile<false><<<dim3(4, 2, 1), 256, 0, stream>>>(W_gnn, W_root, Wc, nullptr,
        128, 256, 256, 256, 256, 512, 256);
    gemm_tile<false><<<dim3(4, 2, 1), 256, 0, stream>>>(W_gnn, W_nbr, Wc + 256, nullptr,
        128, 256, 256, 256, 256, 512, 256);
    // 2. fused conv GEMM (f32): xrn = x @ Wc + bc2
    gemm_f32_big<<<dim3(4, 200), 256, 0, stream>>>(x, Wc, xrn, bc2,
        N_NODES, 512, 128, 128, 512, 512);
    // 3. merged dual-CSR build + merged fwd/bwd aggregation (emits xc + xcb)
    zero_i32<<<dim3(200), 256, 0, stream>>>(counts_d, 51200);   // counts_d+counts_s contiguous
    hist2_kernel<<<dim3(1600), 256, 0, stream>>>(ei0, ei1, counts_d, counts_s, E_EDGE);
    scan_chunk2<<<dim3(200), 256, 0, stream>>>(counts_d, counts_s, rowptr_d, rowptr_s,
                                               tops_d, tops_s, 25600);
    scan_tops2<<<dim3(2), 128, 0, stream>>>(tops_d, tops_s, 100);
    scan_fixup2<<<dim3(200), 256, 0, stream>>>(counts_d, counts_s, rowptr_d, rowptr_s,
                                               cursor_d, cursor_s, tops_d, tops_s, 25600);
    scatter2_kernel<<<dim3(1600), 256, 0, stream>>>(ei0, ei1, cursor_d, cursor_s,
                                                    sorted_d, sorted_s, E_EDGE);
    agg_conv2<<<dim3(25600), 512, 0, stream>>>(xrn, rowptr_d, sorted_d,
                                               rowptr_s, sorted_s, xc, xcb);
    // 5. h1 = xc@W1 + b1 (exact f32; xrn dead -> h1m overlays region A)
    gemm_f32_big<<<dim3(4, 200), 256, 0, stream>>>(xc, W1, h1m, b1,
        N_NODES, 512, 512, 512, 512, 512);
    // 6. per-column layernorm stats
    colstat_kernel<<<dim3(200), 512, 0, stream>>>(h1m, colsum, colsq);
    finalize_stats<<<dim3(1), 512, 0, stream>>>(colsum, colsq, gamma, beta, scalev, shiftv);
    // 7. fused norm+relu+pool, then x_g = P@W2 + b2 (f32)
    fused_norm_pool<<<dim3(256), 512, 0, stream>>>(h1m, scalev, shiftv, P);
    gemm_tile<false><<<dim3(8, 4, 1), 256, 0, stream>>>(P, W2, x_g, b2,
        256, 512, 512, 512, 512, 512, 512);
    // h1m dead: overlay casts for chaos-safe MFMA GEMMs
    transcast<<<dim3(500, 8), 256, 0, stream>>>(W_fc, Wfct, 512, V_OUT);
    cast_strided<<<dim3(50, 100), 256, 0, stream>>>(W_alm, Walmb, 51200, 51712L, 512L);
    // 8. hW = xc_flat(256x51200) @ Wh^T -- bf16 MFMA split-K (100 chunks)
    mfma_gemm<<<dim3(1, 2, 100), 256, 0, stream>>>(xcb, Walmb, hW, nullptr,
        256, 100, 51200, 51200, 51200, 100, 512);
    // 9. alpha and new_c (f32 xc)
    alpha_kernel<<<dim3(512), 128, 0, stream>>>(sW, hW, b_alm, alphav);
    newc_kernel<<<dim3(32, 2), 512, 0, stream>>>(alphav, xc, newc);
    // 10. LSTM input projection (f32; xcb dead -> inp0 overlays)
    gemm_tile<true><<<dim3(32, 4, 1), 256, 0, stream>>>(x_g, Wih0, inp0, b0s,
        256, 2048, 512, 512, 512, 2048, 512);
    // 11. persistent 2-layer LSTM (64 blocks; minimal poll population)
    lstm_init_kernel<<<dim3(64), 512, 0, stream>>>(h0, h0st, h1st);
    lstm_kernel<<<dim3(64), 512, 0, stream>>>(inp0, Whh0, Wih1, Whh1, b1s, newc,
                                              h0st, h1st);
    // 12. preds = outs1 @ W_fc + b_fc -- bf16 MFMA (leaf)
    castbf<<<dim3(128), 256, 0, stream>>>(h1st + 512, ob, 131072L);
    mfma_gemm<<<dim3(250, 2, 1), 256, 0, stream>>>(ob, Wfct, out, b_fc,
        256, V_OUT, 512, 512, 512, V_OUT, 512);
}

// Round 14
// 1882.684 us; speedup vs baseline: 2.3530x; 1.0061x over previous
//
#include <hip/hip_runtime.h>
#include <math.h>

#define N_NODES 25600
#define F_IN    128
#define H_GNN   256
#define D_MLP   512
#define E_EDGE  409600
#define B_GR    256
#define NPG_    100
#define R_LSTM  512
#define V_OUT   32000

typedef __bf16 bf16x8 __attribute__((ext_vector_type(8)));
typedef float  f32x4  __attribute__((ext_vector_type(4)));
typedef unsigned short u16x8 __attribute__((ext_vector_type(8)));

__device__ __forceinline__ unsigned short f2bf(float x) {
    unsigned u = __builtin_bit_cast(unsigned, x);
    unsigned r = (u + 0x7FFFu + ((u >> 16) & 1u)) >> 16;
    return (unsigned short)r;
}

// ---------------------------------------------------------------------------
// Generic f32 tiled GEMM — small GEMMs (weight folds, W2, inp0).
// ---------------------------------------------------------------------------
template<bool TRANSB>
__global__ __launch_bounds__(256)
void gemm_tile(const float* __restrict__ A, const float* __restrict__ B,
               float* __restrict__ C, const float* __restrict__ bias,
               int M, int N, int K, int lda, int ldb, int ldc, int kChunk)
{
    __shared__ float As[16][68];
    __shared__ float Bs[16][68];
    const int tid = threadIdx.x;
    const int n0 = blockIdx.x * 64;
    const int m0 = blockIdx.y * 64;
    const int z  = blockIdx.z;
    const int k0 = z * kChunk;
    const int k1 = min(K, k0 + kChunk);
    const int ty = tid >> 4, tx = tid & 15;
    float acc[4][4] = {};

    for (int kb = k0; kb < k1; kb += 16) {
        {
            const int r = tid >> 4, c = tid & 15;
            #pragma unroll
            for (int i = 0; i < 4; ++i) {
                int rr = r + i * 16;
                int gm = m0 + rr, gk = kb + c;
                As[c][rr] = (gm < M && gk < k1) ? A[gm * lda + gk] : 0.f;
            }
        }
        if (!TRANSB) {
            const int r = tid >> 6, c = tid & 63;
            #pragma unroll
            for (int i = 0; i < 4; ++i) {
                int rr = r + i * 4;
                int gk = kb + rr, gn = n0 + c;
                Bs[rr][c] = (gk < k1 && gn < N) ? B[gk * ldb + gn] : 0.f;
            }
        } else {
            const int r = tid & 15, c = tid >> 4;
            #pragma unroll
            for (int i = 0; i < 4; ++i) {
                int cc = c + i * 16;
                int gk = kb + r, gn = n0 + cc;
                Bs[r][cc] = (gk < k1 && gn < N) ? B[gn * ldb + gk] : 0.f;
            }
        }
        __syncthreads();
        #pragma unroll
        for (int kk = 0; kk < 16; ++kk) {
            float a[4], b[4];
            #pragma unroll
            for (int i = 0; i < 4; ++i) a[i] = As[kk][ty * 4 + i];
            #pragma unroll
            for (int j = 0; j < 4; ++j) b[j] = Bs[kk][tx * 4 + j];
            #pragma unroll
            for (int i = 0; i < 4; ++i)
                #pragma unroll
                for (int j = 0; j < 4; ++j)
                    acc[i][j] = fmaf(a[i], b[j], acc[i][j]);
        }
        __syncthreads();
    }

    const bool split = (gridDim.z > 1);
    #pragma unroll
    for (int i = 0; i < 4; ++i) {
        int gm = m0 + ty * 4 + i;
        if (gm >= M) continue;
        #pragma unroll
        for (int j = 0; j < 4; ++j) {
            int gn = n0 + tx * 4 + j;
            if (gn >= N) continue;
            float v = acc[i][j];
            if (bias != nullptr && z == 0) v += bias[gn];
            if (split) atomicAdd(&C[gm * ldc + gn], v);
            else       C[gm * ldc + gn] = v;
        }
    }
}

// ---------------------------------------------------------------------------
// Big-tile f32 GEMM: 128x128 tile, 8x8 micro-tile, BK=16, exact f32.
// Per-thread k-order identical to BK=8 version (bitwise-same results).
// ---------------------------------------------------------------------------
__global__ __launch_bounds__(256)
void gemm_f32_big(const float* __restrict__ A, const float* __restrict__ B,
                  float* __restrict__ C, const float* __restrict__ bias,
                  int M, int N, int K, int lda, int ldb, int ldc)
{
    __shared__ float As[16][128];
    __shared__ float Bs[16][128];
    const int tid = threadIdx.x;
    const int tx = tid & 15, ty = tid >> 4;
    const int n0 = blockIdx.x * 128, m0 = blockIdx.y * 128;
    float acc[8][8] = {};

    for (int kb = 0; kb < K; kb += 16) {
        {   // A tile: 128 rows x 16 k; thread t: row t>>1, k-cols (t&1)*8..+8
            int r = tid >> 1, cb = (tid & 1) * 8;
            float4 v0 = *(const float4*)(A + (long)(m0 + r) * lda + kb + cb);
            float4 v1 = *(const float4*)(A + (long)(m0 + r) * lda + kb + cb + 4);
            As[cb + 0][r] = v0.x; As[cb + 1][r] = v0.y;
            As[cb + 2][r] = v0.z; As[cb + 3][r] = v0.w;
            As[cb + 4][r] = v1.x; As[cb + 5][r] = v1.y;
            As[cb + 6][r] = v1.z; As[cb + 7][r] = v1.w;
        }
        {   // B tile: 16 k x 128 cols; thread t: k-row t>>4, cols (t&15)*8..+8
            int r = tid >> 4, cb = (tid & 15) * 8;
            *(float4*)&Bs[r][cb]     = *(const float4*)(B + (long)(kb + r) * ldb + n0 + cb);
            *(float4*)&Bs[r][cb + 4] = *(const float4*)(B + (long)(kb + r) * ldb + n0 + cb + 4);
        }
        __syncthreads();
        #pragma unroll
        for (int kk = 0; kk < 16; ++kk) {
            float a[8], b[8];
            *(float4*)&a[0] = *(const float4*)&As[kk][ty * 8];
            *(float4*)&a[4] = *(const float4*)&As[kk][ty * 8 + 4];
            *(float4*)&b[0] = *(const float4*)&Bs[kk][tx * 8];
            *(float4*)&b[4] = *(const float4*)&Bs[kk][tx * 8 + 4];
            #pragma unroll
            for (int i = 0; i < 8; ++i)
                #pragma unroll
                for (int j = 0; j < 8; ++j)
                    acc[i][j] = fmaf(a[i], b[j], acc[i][j]);
        }
        __syncthreads();
    }

    #pragma unroll
    for (int i = 0; i < 8; ++i) {
        int gm = m0 + ty * 8 + i;
        #pragma unroll
        for (int j = 0; j < 8; j += 4) {
            int gn = n0 + tx * 8 + j;
            float4 v = {acc[i][j], acc[i][j+1], acc[i][j+2], acc[i][j+3]};
            if (bias != nullptr) {
                v.x += bias[gn]; v.y += bias[gn + 1];
                v.z += bias[gn + 2]; v.w += bias[gn + 3];
            }
            *(float4*)(C + (long)gm * ldc + gn) = v;
        }
    }
}

// ---------------------------------------------------------------------------
// bf16 MFMA GEMM (plain): chaos-safe GEMMs only (hW, preds).
// ---------------------------------------------------------------------------
__global__ __launch_bounds__(256)
void mfma_gemm(const unsigned short* __restrict__ A,
               const unsigned short* __restrict__ Bt,
               float* __restrict__ C, const float* __restrict__ bias,
               int M, int N, int K, int lda, int ldb, int ldc, int kChunk)
{
    __shared__ unsigned short As[128][40];
    __shared__ unsigned short Bs[128][40];
    const int tid  = threadIdx.x;
    const int lane = tid & 63;
    const int wv   = tid >> 6;
    const int wr   = wv >> 1, wc = wv & 1;
    const int n0 = blockIdx.x * 128;
    const int m0 = blockIdx.y * 128;
    const int z  = blockIdx.z;
    const int k0 = z * kChunk;
    const int k1 = min(K, k0 + kChunk);

    const int srow = tid >> 2;
    const int skoff = (tid & 3) * 8;

    f32x4 acc[4][4] = {};

    for (int kb = k0; kb < k1; kb += 32) {
        #pragma unroll
        for (int p = 0; p < 2; ++p) {
            int row = p * 64 + srow;
            u16x8 va = *(const u16x8*)(A + (long)(m0 + row) * lda + kb + skoff);
            *(u16x8*)&As[row][skoff] = va;
            int gb = n0 + row;
            u16x8 vb = {0, 0, 0, 0, 0, 0, 0, 0};
            if (gb < N) vb = *(const u16x8*)(Bt + (long)gb * ldb + kb + skoff);
            *(u16x8*)&Bs[row][skoff] = vb;
        }
        __syncthreads();
        bf16x8 af[4], bfr[4];
        #pragma unroll
        for (int fm = 0; fm < 4; ++fm)
            af[fm] = *(const bf16x8*)&As[wr * 64 + fm * 16 + (lane & 15)][(lane >> 4) * 8];
        #pragma unroll
        for (int fn = 0; fn < 4; ++fn)
            bfr[fn] = *(const bf16x8*)&Bs[wc * 64 + fn * 16 + (lane & 15)][(lane >> 4) * 8];
        #pragma unroll
        for (int fm = 0; fm < 4; ++fm)
            #pragma unroll
            for (int fn = 0; fn < 4; ++fn)
                acc[fm][fn] = __builtin_amdgcn_mfma_f32_16x16x32_bf16(
                    af[fm], bfr[fn], acc[fm][fn], 0, 0, 0);
        __syncthreads();
    }

    const bool split = (gridDim.z > 1);
    #pragma unroll
    for (int fm = 0; fm < 4; ++fm) {
        int row = m0 + wr * 64 + fm * 16 + ((lane >> 4) << 2);
        #pragma unroll
        for (int fn = 0; fn < 4; ++fn) {
            int col = n0 + wc * 64 + fn * 16 + (lane & 15);
            if (col >= N) continue;
            f32x4 v = acc[fm][fn];
            #pragma unroll
            for (int r = 0; r < 4; ++r) {
                float o = v[r];
                if (bias != nullptr && z == 0) o += bias[col];
                if (split) atomicAdd(&C[(long)(row + r) * ldc + col], o);
                else       C[(long)(row + r) * ldc + col] = o;
            }
        }
    }
}

// ---------------------------------------------------------------------------
// cast / transpose kernels
// ---------------------------------------------------------------------------
__global__ void cast_strided(const float* __restrict__ in, unsigned short* __restrict__ out,
                             int cols, long ldin, long off) {
    const int r = blockIdx.y;
    int c = (blockIdx.x * blockDim.x + threadIdx.x) * 4;
    if (c < cols) {
        float4 v = *(const float4*)(in + (long)r * ldin + off + c);
        ushort4 o;
        o.x = f2bf(v.x); o.y = f2bf(v.y); o.z = f2bf(v.z); o.w = f2bf(v.w);
        *(ushort4*)(out + (long)r * cols + c) = o;
    }
}
__global__ __launch_bounds__(256)
void transcast(const float* __restrict__ in, unsigned short* __restrict__ out,
               int R, int C) {
    __shared__ unsigned short t[64][72];
    const int c0 = blockIdx.x * 64, r0 = blockIdx.y * 64;
    const int tid = threadIdx.x;
    const int rr = tid >> 2, cg = (tid & 3) * 16;
    #pragma unroll
    for (int i = 0; i < 4; ++i) {
        float4 v = *(const float4*)(in + (long)(r0 + rr) * C + c0 + cg + i * 4);
        t[cg + i * 4 + 0][rr] = f2bf(v.x);
        t[cg + i * 4 + 1][rr] = f2bf(v.y);
        t[cg + i * 4 + 2][rr] = f2bf(v.z);
        t[cg + i * 4 + 3][rr] = f2bf(v.w);
    }
    __syncthreads();
    const int cc = tid >> 2, kg = (tid & 3) * 16;
    #pragma unroll
    for (int i = 0; i < 2; ++i) {
        u16x8 v = *(const u16x8*)&t[cc][kg + i * 8];
        *(u16x8*)(out + (long)(c0 + cc) * R + r0 + kg + i * 8) = v;
    }
}

// ---------------------------------------------------------------------------
// fused small-prep: b0s, b1s, bc2, sW + zero colsum/colsq/newc/hW/counts.
// grid = 311 blocks x 256.
// ---------------------------------------------------------------------------
__global__ __launch_bounds__(256)
void prep_kernel(const float* __restrict__ bih0, const float* __restrict__ bhh0,
                 const float* __restrict__ bih1, const float* __restrict__ bhh1,
                 const float* __restrict__ b_conv, const float* __restrict__ c0,
                 const float* __restrict__ W_alm,
                 float* b0s, float* b1s, float* bc2, float* sW,
                 float* colsum, float* colsq, float* newc, float* hW,
                 int* counts) {
    const int b = blockIdx.x, t = threadIdx.x;
    if (b < 8) {
        int i = b * 256 + t;
        b0s[i] = bih0[i] + bhh0[i];
        b1s[i] = bih1[i] + bhh1[i];
    } else if (b == 8) {
        bc2[t] = b_conv[t];
        bc2[t + 256] = 0.f;
    } else if (b == 9) {
        if (t < 2 * NPG_) {
            int l = t / NPG_, p = t % NPG_;
            float s = 0.f;
            for (int k = 0; k < R_LSTM; ++k)
                s += c0[l * R_LSTM + k] * W_alm[(long)p * 51712 + k];
            sW[l * NPG_ + p] = s;
        }
    } else if (b == 10) {
        for (int i = t; i < 512; i += 256) { colsum[i] = 0.f; colsq[i] = 0.f; }
        for (int i = t; i < 1024; i += 256) newc[i] = 0.f;
    } else if (b < 111) {
        int i = (b - 11) * 256 + t;          // blocks 11..110 -> 25600
        if (i < 25600) hW[i] = 0.f;
    } else {
        int i = (b - 111) * 256 + t;         // blocks 111..310 -> 51200 ints
        if (i < 51200) counts[i] = 0;
    }
}

// ---- merged dual-CSR build (dst-keyed for fwd conv, src-keyed for bwd) ----
__global__ void hist2_kernel(const int* __restrict__ ei0, const int* __restrict__ ei1,
                             int* counts_d, int* counts_s, int E) {
    int i = blockIdx.x * blockDim.x + threadIdx.x;
    if (i < E) {
        atomicAdd(&counts_d[ei1[i]], 1);
        atomicAdd(&counts_s[ei0[i]], 1);
    }
}
__global__ __launch_bounds__(256)
void scan_chunk2(const int* __restrict__ counts_d, const int* __restrict__ counts_s,
                 int* rowptr_d, int* rowptr_s, int* tops_d, int* tops_s, int n) {
    __shared__ int buf[256];
    const int half = blockIdx.x >= 100;
    const int chunk = half ? blockIdx.x - 100 : blockIdx.x;
    const int* counts = half ? counts_s : counts_d;
    int* rowptr = half ? rowptr_s : rowptr_d;
    int* tops   = half ? tops_s   : tops_d;
    const int tid = threadIdx.x;
    int i = chunk * 256 + tid;
    int v = (i < n) ? counts[i] : 0;
    buf[tid] = v;
    __syncthreads();
    for (int off = 1; off < 256; off <<= 1) {
        int add = (tid >= off) ? buf[tid - off] : 0;
        __syncthreads();
        buf[tid] += add;
        __syncthreads();
    }
    if (i < n) rowptr[i + 1] = buf[tid];
    if (tid == 255) tops[chunk] = buf[255];
}
// fixup with inline tops-prefix (tops holds raw per-chunk totals)
__global__ __launch_bounds__(256)
void scan_fixup2(const int* __restrict__ counts_d, const int* __restrict__ counts_s,
                 int* rowptr_d, int* rowptr_s,
                 int* cursor_d, int* cursor_s,
                 const int* __restrict__ tops_d, const int* __restrict__ tops_s,
                 int n) {
    const int half = blockIdx.x >= 100;
    const int chunk = half ? blockIdx.x - 100 : blockIdx.x;
    const int* counts = half ? counts_s : counts_d;
    const int* tops   = half ? tops_s   : tops_d;
    int* rowptr = half ? rowptr_s : rowptr_d;
    int* cursor = half ? cursor_s : cursor_d;
    __shared__ int base_s;
    if (threadIdx.x == 0) {
        int b = 0;
        for (int j = 0; j < chunk; ++j) b += tops[j];
        base_s = b;
    }
    __syncthreads();
    int i = chunk * 256 + threadIdx.x;
    if (i < n) {
        int r = rowptr[i + 1] + base_s;
        rowptr[i + 1] = r;
        cursor[i] = r - counts[i];
        if (i == 0) rowptr[0] = 0;
    }
}
__global__ void scatter2_kernel(const int* __restrict__ ei0, const int* __restrict__ ei1,
                                int* cursor_d, int* cursor_s,
                                int* sorted_d, int* sorted_s, int E) {
    int i = blockIdx.x * blockDim.x + threadIdx.x;
    if (i < E) {
        int s = ei0[i], d = ei1[i];
        int pd = atomicAdd(&cursor_d[d], 1);
        sorted_d[pd] = s;
        int ps = atomicAdd(&cursor_s[s], 1);
        sorted_s[ps] = d;
    }
}
// merged fwd+bwd aggregation + relu, emitting xc (f32) AND xcb (bf16).
__global__ __launch_bounds__(512)
void agg_conv2(const float* __restrict__ xrn,
               const int* __restrict__ rowptr_d, const int* __restrict__ sorted_d,
               const int* __restrict__ rowptr_s, const int* __restrict__ sorted_s,
               float* __restrict__ xc, unsigned short* __restrict__ xcb) {
    const int n = blockIdx.x;
    const int tid = threadIdx.x;
    const int c = tid & 255;
    const bool bwd = tid >= 256;
    const int* rowptr = bwd ? rowptr_s : rowptr_d;
    const int* sorted = bwd ? sorted_s : sorted_d;
    float acc = xrn[(long)n * 512 + c];
    const int s = rowptr[n], e = rowptr[n + 1];
    for (int t = s; t < e; ++t)
        acc += xrn[(long)sorted[t] * 512 + 256 + c];
    float r = fmaxf(acc, 0.f);
    long idx = (long)n * 512 + (bwd ? 256 : 0) + c;
    xc[idx] = r;
    xcb[idx] = f2bf(r);
}

__global__ __launch_bounds__(512)
void colstat_kernel(const float* __restrict__ h1, float* colsum, float* colsq) {
    const int c = threadIdx.x;
    const int r0 = blockIdx.x * 128;
    float s = 0.f, s2 = 0.f;
    for (int r = 0; r < 128; ++r) {
        float v = h1[(long)(r0 + r) * D_MLP + c];
        s += v; s2 += v * v;
    }
    atomicAdd(&colsum[c], s);
    atomicAdd(&colsq[c], s2);
}
// fused finalize + layernorm-apply + relu + mean-pool
__global__ __launch_bounds__(512)
void fused_norm_pool(const float* __restrict__ h1,
                     const float* __restrict__ colsum, const float* __restrict__ colsq,
                     const float* __restrict__ gamma, const float* __restrict__ beta,
                     float* __restrict__ P) {
    const int b = blockIdx.x, c = threadIdx.x;
    float m  = colsum[c] * (1.f / N_NODES);
    float vr = colsq[c] * (1.f / N_NODES) - m * m;
    float scv = gamma[c] * rsqrtf(vr + 1e-5f);
    float shv = beta[c] - m * scv;
    float s = 0.f;
    for (int i = 0; i < NPG_; ++i) {
        float v = h1[(long)(b * NPG_ + i) * D_MLP + c];
        s += fmaxf(fmaf(v, scv, shv), 0.f);
    }
    P[b * D_MLP + c] = s * (1.f / NPG_);
}
__global__ __launch_bounds__(128)
void alpha_kernel(const float* __restrict__ sW, const float* __restrict__ hW,
                  const float* __restrict__ b_alm, float* __restrict__ alpha) {
    const int lb = blockIdx.x;
    const int l = lb >> 8, b = lb & 255;
    const int p = threadIdx.x;
    __shared__ float red[128];
    float v = 0.f;
    if (p < NPG_) v = sW[l * NPG_ + p] + hW[b * NPG_ + p] + b_alm[p];
    red[p] = v;
    __syncthreads();
    for (int s = 64; s > 0; s >>= 1) {
        if (p < s) red[p] += red[p + s];
        __syncthreads();
    }
    float inv = 1.f / red[0];
    if (p < NPG_) alpha[lb * NPG_ + p] = v * inv;
}
// both l=0 and l=1 accumulated in ONE xc pass (same per-l fmaf order)
__global__ __launch_bounds__(512)
void newc_kernel(const float* __restrict__ alpha, const float* __restrict__ xc,
                 float* new_c) {
    const int chunk = blockIdx.x, c = threadIdx.x;
    const int r0 = chunk * 800;
    float a0 = 0.f, a1 = 0.f;
    for (int r = r0; r < r0 + 800; ++r) {
        float v = xc[(long)r * D_MLP + c];
        a0 = fmaf(alpha[r], v, a0);
        a1 = fmaf(alpha[N_NODES + r], v, a1);
    }
    atomicAdd(&new_c[c], a0);
    atomicAdd(&new_c[512 + c], a1);
}

// ---------------------------------------------------------------------------
// Persistent 2-layer LSTM, canary sync, precise libm — measured-856µs R7
// structure. Layer-1 epilogue additionally writes bf16 h to ob (plain store,
// off the poll critical path) so the preds GEMM needs no separate cast.
// ---------------------------------------------------------------------------
#define CANARY 0x7FC00000u
#define SPIN_MAX 20000

__device__ __forceinline__ unsigned coh_load_u(const unsigned* p) {
    return __hip_atomic_load(p, __ATOMIC_RELAXED, __HIP_MEMORY_SCOPE_AGENT);
}
__device__ __forceinline__ void coh_store_f(float* p, float v) {
    __hip_atomic_store(p, v, __ATOMIC_RELAXED, __HIP_MEMORY_SCOPE_AGENT);
}

__global__ void lstm_init_kernel(const float* __restrict__ h0,
                                 float* h0buf, float* h1buf) {
    int i = blockIdx.x * blockDim.x + threadIdx.x;
    if (i < 512) { h0buf[i] = h0[i]; h1buf[i] = h0[512 + i]; }
    for (int j = 512 + i; j < 257 * 512; j += gridDim.x * blockDim.x) {
        ((unsigned*)h0buf)[j] = CANARY;
        ((unsigned*)h1buf)[j] = CANARY;
    }
}

__global__ __launch_bounds__(512)
void lstm_kernel(const float* __restrict__ inp0, const float* __restrict__ Whh0,
                 const float* __restrict__ Wih1, const float* __restrict__ Whh1,
                 const float* __restrict__ b1s, const float* __restrict__ new_c,
                 float* h0buf, float* h1buf, unsigned short* __restrict__ ob)
{
    const int tid  = threadIdx.x;
    const int lane = tid & 63;
    const int w    = tid >> 6;
    const int blk  = blockIdx.x;
    const int layer = blk >> 5;
    const int base  = (blk & 31) * 16;
    const int gate  = lane >> 4;
    const int hid   = lane & 15;
    const int rowg  = gate * 512 + base + hid;

    __shared__ float partial[2][8][64];

    if (layer == 0) {
        float wr[64];
        {
            const float4* wp = (const float4*)(Whh0 + (long)rowg * 512 + w * 64);
            #pragma unroll
            for (int i = 0; i < 16; ++i) {
                float4 v = wp[i];
                wr[4*i] = v.x; wr[4*i+1] = v.y; wr[4*i+2] = v.z; wr[4*i+3] = v.w;
            }
        }
        float c = (w == 0 && lane < 16) ? new_c[base + lane] : 0.f;
        const unsigned* src = (const unsigned*)h0buf + w * 64 + lane;
        for (int t = 0; t < 256; ++t) {
            float ipv = (w == 0) ? inp0[t * 2048 + rowg] : 0.f;
            unsigned hu; int guard = 0;
            for (;;) {
                hu = coh_load_u(src + (long)t * 512);
                if (!__any(hu == CANARY)) break;
                if (++guard > SPIN_MAX) break;
                if (guard > 32) __builtin_amdgcn_s_sleep(1);
            }
            float hv = __uint_as_float(hu);
            float acc = 0.f;
            #pragma unroll
            for (int j = 0; j < 64; ++j)
                acc = fmaf(wr[j], __shfl(hv, j), acc);
            partial[t & 1][w][lane] = acc;
            __syncthreads();
            if (w == 0) {
                float g = ipv;
                #pragma unroll
                for (int ww = 0; ww < 8; ++ww) g += partial[t & 1][ww][lane];
                float a = (gate == 2) ? tanhf(g) : 1.f / (1.f + expf(-g));
                float fv = __shfl(a, lane + 16);
                float gv = __shfl(a, lane + 32);
                float ov = __shfl(a, lane + 48);
                if (lane < 16) {
                    c = fv * c + a * gv;
                    float h = ov * tanhf(c);
                    coh_store_f(h0buf + (long)(t + 1) * 512 + base + lane, h);
                }
            }
        }
    } else {
        const float* Wsel = (w < 4) ? Wih1 : Whh1;
        const int koff = (w & 3) * 128;
        float wrA[64], wrB[64];
        {
            const float4* wp = (const float4*)(Wsel + (long)rowg * 512 + koff);
            #pragma unroll
            for (int i = 0; i < 16; ++i) {
                float4 v = wp[i];
                wrA[4*i] = v.x; wrA[4*i+1] = v.y; wrA[4*i+2] = v.z; wrA[4*i+3] = v.w;
            }
            #pragma unroll
            for (int i = 0; i < 16; ++i) {
                float4 v = wp[16 + i];
                wrB[4*i] = v.x; wrB[4*i+1] = v.y; wrB[4*i+2] = v.z; wrB[4*i+3] = v.w;
            }
        }
        float bsum = (w == 0) ? b1s[rowg] : 0.f;
        float c = (w == 0 && lane < 16) ? new_c[512 + base + lane] : 0.f;
        for (int t = 0; t < 256; ++t) {
            const unsigned* xsrc = (w < 4)
                ? (const unsigned*)h0buf + (long)(t + 1) * 512 + koff
                : (const unsigned*)h1buf + (long)t * 512 + koff;
            unsigned hu0, hu1; int guard = 0;
            for (;;) {
                hu0 = coh_load_u(xsrc + lane);
                hu1 = coh_load_u(xsrc + 64 + lane);
                if (!__any((hu0 == CANARY) || (hu1 == CANARY))) break;
                if (++guard > SPIN_MAX) break;
                if (guard > 32) __builtin_amdgcn_s_sleep(1);
            }
            float hv0 = __uint_as_float(hu0), hv1 = __uint_as_float(hu1);
            float acc = 0.f;
            #pragma unroll
            for (int j = 0; j < 64; ++j)
                acc = fmaf(wrA[j], __shfl(hv0, j), acc);
            #pragma unroll
            for (int j = 0; j < 64; ++j)
                acc = fmaf(wrB[j], __shfl(hv1, j), acc);
            partial[t & 1][w][lane] = acc;
            __syncthreads();
            if (w == 0) {
                float g = bsum;
                #pragma unroll
                for (int ww = 0; ww < 8; ++ww) g += partial[t & 1][ww][lane];
                float a = (gate == 2) ? tanhf(g) : 1.f / (1.f + expf(-g));
                float fv = __shfl(a, lane + 16);
                float gv = __shfl(a, lane + 32);
                float ov = __shfl(a, lane + 48);
                if (lane < 16) {
                    c = fv * c + a * gv;
                    float h = ov * tanhf(c);
                    coh_store_f(h1buf + (long)(t + 1) * 512 + base + lane, h);
                    ob[t * 512 + base + lane] = f2bf(h);   // preds input (plain store)
                }
            }
        }
    }
}

// ---------------------------------------------------------------------------
extern "C" void kernel_launch(void* const* d_in, const int* in_sizes, int n_in,
                              void* d_out, int out_size, void* d_ws, size_t ws_size,
                              hipStream_t stream)
{
    const float* x      = (const float*)d_in[0];
    const int*   ei     = (const int*)d_in[1];
    const float* h0     = (const float*)d_in[4];
    const float* c0     = (const float*)d_in[5];
    const float* W_gnn  = (const float*)d_in[6];
    const float* W_root = (const float*)d_in[7];
    const float* W_nbr  = (const float*)d_in[8];
    const float* b_conv = (const float*)d_in[9];
    const float* W1     = (const float*)d_in[10];
    const float* b1     = (const float*)d_in[11];
    const float* gamma  = (const float*)d_in[12];
    const float* beta   = (const float*)d_in[13];
    const float* W2     = (const float*)d_in[14];
    const float* b2     = (const float*)d_in[15];
    const float* W_alm  = (const float*)d_in[16];
    const float* b_alm  = (const float*)d_in[17];
    const float* Wih0   = (const float*)d_in[18];
    const float* Whh0   = (const float*)d_in[19];
    const float* bih0   = (const float*)d_in[20];
    const float* bhh0   = (const float*)d_in[21];
    const float* Wih1   = (const float*)d_in[22];
    const float* Whh1   = (const float*)d_in[23];
    const float* bih1   = (const float*)d_in[24];
    const float* bhh1   = (const float*)d_in[25];
    const float* W_fc   = (const float*)d_in[26];
    const float* b_fc   = (const float*)d_in[27];
    float* out = (float*)d_out;
    float* ws  = (float*)d_ws;

    const int* ei0 = ei;
    const int* ei1 = ei + E_EDGE;

    // ---- workspace layout (float offsets) ----
    float* xrn = ws;
    float* h1m = ws;
    unsigned short* Wfct  = (unsigned short*)ws;                 // 32000x512 bf16
    unsigned short* Walmb = (unsigned short*)(ws + 8500000L);    // 100x51200 bf16
    unsigned short* ob    = (unsigned short*)(ws + 11200000L);   // 256x512 bf16
    float* xc = ws + 13107200L;                                  // 25600x512 f32
    long o = 26214400L;
    float* Wc    = ws + o; o += 65536;
    int*   counts_d = (int*)(ws + o); o += 25600;
    int*   counts_s = (int*)(ws + o); o += 25600;
    int*   rowptr_d = (int*)(ws + o); o += 25601;
    int*   rowptr_s = (int*)(ws + o); o += 25601;
    int*   cursor_d = (int*)(ws + o); o += 25600;
    int*   cursor_s = (int*)(ws + o); o += 25600;
    int*   sorted_d = (int*)(ws + o); o += 409600;
    int*   sorted_s = (int*)(ws + o); o += 409600;
    int*   tops_d   = (int*)(ws + o); o += 128;
    int*   tops_s   = (int*)(ws + o); o += 128;
    float* colsum= ws + o; o += 512;
    float* colsq = ws + o; o += 512;
    float* P     = ws + o; o += 131072;
    float* x_g   = ws + o; o += 131072;
    float* hW    = ws + o; o += 25600;
    float* sW    = ws + o; o += 200;
    float* alphav= ws + o; o += 51200;
    float* newc  = ws + o; o += 1024;
    float* b0s   = ws + o; o += 2048;
    float* b1s   = ws + o; o += 2048;
    float* bc2   = ws + o; o += 512;
    unsigned short* xcb = (unsigned short*)(ws + o);
    float* inp0  = ws + o;            // overlays xcb (xcb dead before inp0 write)
    float* h0st  = ws + o + 524288;
    float* h1st  = ws + o + 655872;
    o += 6553600;

    // 0. fused prep (biases, bc2, sW + zero colsum/colsq/newc/hW/counts)
    prep_kernel<<<dim3(311), 256, 0, stream>>>(bih0, bhh0, bih1, bhh1, b_conv, c0,
                                               W_alm, b0s, b1s, bc2, sW,
                                               colsum, colsq, newc, hW, counts_d);
    // 1. conv weight folding
    gemm_tile<false><<<dim3(4, 2, 1), 256, 0, stream>>>(W_gnn, W_root, Wc, nullptr,
        128, 256, 256, 256, 256, 512, 256);
    gemm_tile<false><<<dim3(4, 2, 1), 256, 0, stream>>>(W_gnn, W_nbr, Wc + 256, nullptr,
        128, 256, 256, 256, 256, 512, 256);
    // 2. fused conv GEMM (f32): xrn = x @ Wc + bc2
    gemm_f32_big<<<dim3(4, 200), 256, 0, stream>>>(x, Wc, xrn, bc2,
        N_NODES, 512, 128, 128, 512, 512);
    // 3. merged dual-CSR build + merged fwd/bwd aggregation (emits xc + xcb)
    hist2_kernel<<<dim3(1600), 256, 0, stream>>>(ei0, ei1, counts_d, counts_s, E_EDGE);
    scan_chunk2<<<dim3(200), 256, 0, stream>>>(counts_d, counts_s, rowptr_d, rowptr_s,
                                               tops_d, tops_s, 25600);
    scan_fixup2<<<dim3(200), 256, 0, stream>>>(counts_d, counts_s, rowptr_d, rowptr_s,
                                               cursor_d, cursor_s, tops_d, tops_s, 25600);
    scatter2_kernel<<<dim3(1600), 256, 0, stream>>>(ei0, ei1, cursor_d, cursor_s,
                                                    sorted_d, sorted_s, E_EDGE);
    agg_conv2<<<dim3(25600), 512, 0, stream>>>(xrn, rowptr_d, sorted_d,
                                               rowptr_s, sorted_s, xc, xcb);
    // 5. h1 = xc@W1 + b1 (exact f32; xrn dead -> h1m overlays region A)
    gemm_f32_big<<<dim3(4, 200), 256, 0, stream>>>(xc, W1, h1m, b1,
        N_NODES, 512, 512, 512, 512, 512);
    // 6. column stats, then fused finalize+norm+relu+pool, x_g = P@W2 + b2
    colstat_kernel<<<dim3(200), 512, 0, stream>>>(h1m, colsum, colsq);
    fused_norm_pool<<<dim3(256), 512, 0, stream>>>(h1m, colsum, colsq, gamma, beta, P);
    gemm_tile<false><<<dim3(8, 4, 1), 256, 0, stream>>>(P, W2, x_g, b2,
        256, 512, 512, 512, 512, 512, 512);
    // h1m dead: overlay casts for chaos-safe MFMA GEMMs
    transcast<<<dim3(500, 8), 256, 0, stream>>>(W_fc, Wfct, 512, V_OUT);
    cast_strided<<<dim3(50, 100), 256, 0, stream>>>(W_alm, Walmb, 51200, 51712L, 512L);
    // 8. hW = xc_flat(256x51200) @ Wh^T -- bf16 MFMA split-K (100 chunks)
    mfma_gemm<<<dim3(1, 2, 100), 256, 0, stream>>>(xcb, Walmb, hW, nullptr,
        256, 100, 51200, 51200, 51200, 100, 512);
    // 9. alpha and new_c (f32 xc, single pass for both l)
    alpha_kernel<<<dim3(512), 128, 0, stream>>>(sW, hW, b_alm, alphav);
    newc_kernel<<<dim3(32), 512, 0, stream>>>(alphav, xc, newc);
    // 10. LSTM input projection (f32; xcb dead -> inp0 overlays)
    gemm_tile<true><<<dim3(32, 4, 1), 256, 0, stream>>>(x_g, Wih0, inp0, b0s,
        256, 2048, 512, 512, 512, 2048, 512);
    // 11. persistent 2-layer LSTM (64 blocks; writes ob directly)
    lstm_init_kernel<<<dim3(64), 512, 0, stream>>>(h0, h0st, h1st);
    lstm_kernel<<<dim3(64), 512, 0, stream>>>(inp0, Whh0, Wih1, Whh1, b1s, newc,
                                              h0st, h1st, ob);
    // 12. preds = outs1 @ W_fc + b_fc -- bf16 MFMA (leaf)
    mfma_gemm<<<dim3(250, 2, 1), 256, 0, stream>>>(ob, Wfct, out, b_fc,
        256, V_OUT, 512, 512, 512, V_OUT, 512);
}